// Round 9
// baseline (289.627 us; speedup 1.0000x reference)
//
#include <hip/hip_runtime.h>
#include <hip/hip_bf16.h>

typedef unsigned short u16;
typedef unsigned int u32;
typedef __attribute__((ext_vector_type(4))) float f32x4;
typedef __attribute__((ext_vector_type(4))) u32 u32x4;
typedef __attribute__((ext_vector_type(8))) __bf16 bf16x8;

#define SQ 3072
#define NH 4
#define DH 32

static __device__ __forceinline__ u16 f2bf(float f) {
  return __builtin_bit_cast(u16, (__bf16)f);
}
static __device__ __forceinline__ u32 pk2(float a, float b) {
  return (u32)f2bf(a) | ((u32)f2bf(b) << 16);
}
static __device__ __forceinline__ bf16x8 ld8(const u16* p) {
  return __builtin_bit_cast(bf16x8, *reinterpret_cast<const u32x4*>(p));
}
static __device__ __forceinline__ f32x4 mfma16(bf16x8 a, bf16x8 b, f32x4 c) {
  return __builtin_amdgcn_mfma_f32_16x16x32_bf16(a, b, c, 0, 0, 0);
}
static __device__ __forceinline__ float sigm(float x) { return 1.0f / (1.0f + __expf(-x)); }
static __device__ __forceinline__ float red8(float v) {
  v += __shfl_xor(v, 1); v += __shfl_xor(v, 2); v += __shfl_xor(v, 4);
  return v;
}

// A: 32x128 bf16 in LDS (row stride 136). B: WT[cout][k] bf16 (128x128, row stride 128).
static __device__ __forceinline__ void gemm32x128(
    const u16* a, const u16* wt, int lr, int lg, int wave, f32x4 d[2][2]) {
  f32x4 z = {0.f, 0.f, 0.f, 0.f};
  d[0][0] = z; d[0][1] = z; d[1][0] = z; d[1][1] = z;
#pragma unroll
  for (int kc = 0; kc < 4; ++kc) {
    int ko = kc * 32 + lg * 8;
    bf16x8 a0 = ld8(a + lr * 136 + ko);
    bf16x8 a1 = ld8(a + (16 + lr) * 136 + ko);
    bf16x8 b0 = ld8(wt + ((wave * 2 + 0) * 16 + lr) * 128 + ko);
    bf16x8 b1 = ld8(wt + ((wave * 2 + 1) * 16 + lr) * 128 + ko);
    d[0][0] = mfma16(a0, b0, d[0][0]);
    d[1][0] = mfma16(a1, b0, d[1][0]);
    d[0][1] = mfma16(a0, b1, d[0][1]);
    d[1][1] = mfma16(a1, b1, d[1][1]);
  }
}

struct PrepSrc { const float* p[10]; };

__global__ __launch_bounds__(256) void prep(PrepSrc s, u16* __restrict__ dst) {
  int bid = blockIdx.x;
  int mm = bid >> 6;
  int idx = ((bid & 63) << 8) + threadIdx.x;  // = cout*128 + k
  int co = idx >> 7, k = idx & 127;
  dst[mm * 16384 + idx] = f2bf(s.p[mm][k * 128 + co]);
}

__global__ __launch_bounds__(256) void rowblock_q(
    const float* __restrict__ x, const float* __restrict__ cond,
    const float* __restrict__ gamma, const float* __restrict__ bs,
    const float* __restrict__ bq, const float* __restrict__ bzc,
    const u16* __restrict__ WT,
    u16* __restrict__ qbf, float* __restrict__ gate, float* __restrict__ zc) {
  __shared__ float xnf[32 * 132];
  __shared__ u16 a_cn[32 * 136];
  __shared__ u16 a_raw[32 * 136];
  __shared__ u16 a_xa[32 * 136];
  const int tid = threadIdx.x;
  const int rl = tid >> 3, sub = tid & 7, c0 = sub * 16;
  const size_t grow = (size_t)blockIdx.x * 32 + rl;

  {
    float xs[16];
    const float4* xr = reinterpret_cast<const float4*>(x + grow * 128 + c0);
#pragma unroll
    for (int i = 0; i < 4; ++i) { float4 t = xr[i]; xs[4*i]=t.x; xs[4*i+1]=t.y; xs[4*i+2]=t.z; xs[4*i+3]=t.w; }
    float s = 0.f;
#pragma unroll
    for (int i = 0; i < 16; ++i) s += xs[i];
    float mean = red8(s) * (1.f / 128.f);
    float vs = 0.f;
#pragma unroll
    for (int i = 0; i < 16; ++i) { float dd = xs[i] - mean; vs += dd * dd; }
    float rstd = rsqrtf(red8(vs) * (1.f / 128.f) + 1e-5f);
    float4* xw = reinterpret_cast<float4*>(&xnf[rl * 132 + c0]);
#pragma unroll
    for (int i = 0; i < 4; ++i) {
      float4 t;
      t.x = (xs[4*i+0] - mean) * rstd; t.y = (xs[4*i+1] - mean) * rstd;
      t.z = (xs[4*i+2] - mean) * rstd; t.w = (xs[4*i+3] - mean) * rstd;
      xw[i] = t;
    }
  }
  {
    float cs[16], gs[16];
    const float4* cr = reinterpret_cast<const float4*>(cond + grow * 128 + c0);
    const float4* gr = reinterpret_cast<const float4*>(gamma + c0);
#pragma unroll
    for (int i = 0; i < 4; ++i) { float4 t = cr[i]; cs[4*i]=t.x; cs[4*i+1]=t.y; cs[4*i+2]=t.z; cs[4*i+3]=t.w; }
#pragma unroll
    for (int i = 0; i < 4; ++i) { float4 t = gr[i]; gs[4*i]=t.x; gs[4*i+1]=t.y; gs[4*i+2]=t.z; gs[4*i+3]=t.w; }
    float s = 0.f;
#pragma unroll
    for (int i = 0; i < 16; ++i) s += cs[i];
    float mean = red8(s) * (1.f / 128.f);
    float vs = 0.f;
#pragma unroll
    for (int i = 0; i < 16; ++i) { float dd = cs[i] - mean; vs += dd * dd; }
    float rstd = rsqrtf(red8(vs) * (1.f / 128.f) + 1e-5f);
    float cn[16];
#pragma unroll
    for (int i = 0; i < 16; ++i) cn[i] = (cs[i] - mean) * rstd * gs[i];
    u32x4* cw = reinterpret_cast<u32x4*>(&a_cn[rl * 136 + c0]);
    u32x4 w0 = {pk2(cn[0],cn[1]), pk2(cn[2],cn[3]), pk2(cn[4],cn[5]), pk2(cn[6],cn[7])};
    u32x4 w1 = {pk2(cn[8],cn[9]), pk2(cn[10],cn[11]), pk2(cn[12],cn[13]), pk2(cn[14],cn[15])};
    cw[0] = w0; cw[1] = w1;
    u32x4* rw = reinterpret_cast<u32x4*>(&a_raw[rl * 136 + c0]);
    u32x4 r0 = {pk2(cs[0],cs[1]), pk2(cs[2],cs[3]), pk2(cs[4],cs[5]), pk2(cs[6],cs[7])};
    u32x4 r1 = {pk2(cs[8],cs[9]), pk2(cs[10],cs[11]), pk2(cs[12],cs[13]), pk2(cs[14],cs[15])};
    rw[0] = r0; rw[1] = r1;
  }
  __syncthreads();
  const int lane = tid & 63, wave = tid >> 6, lr = lane & 15, lg = lane >> 4;
  f32x4 dS[2][2], dB[2][2];
  gemm32x128(a_cn, WT + 0 * 16384, lr, lg, wave, dS);
  gemm32x128(a_cn, WT + 1 * 16384, lr, lg, wave, dB);
#pragma unroll
  for (int mt = 0; mt < 2; ++mt)
#pragma unroll
    for (int j = 0; j < 2; ++j)
#pragma unroll
      for (int r = 0; r < 4; ++r) {
        int col = (wave * 2 + j) * 16 + lr;
        int rowl = mt * 16 + lg * 4 + r;
        float sc = dS[mt][j][r] + bs[col];
        float xa = sigm(sc) * xnf[rowl * 132 + col] + dB[mt][j][r];
        a_xa[rowl * 136 + col] = f2bf(xa);
      }
  __syncthreads();
  f32x4 dQ[2][2], dG[2][2], dZ[2][2];
  gemm32x128(a_xa, WT + 2 * 16384, lr, lg, wave, dQ);
  gemm32x128(a_xa, WT + 3 * 16384, lr, lg, wave, dG);
  gemm32x128(a_raw, WT + 4 * 16384, lr, lg, wave, dZ);
#pragma unroll
  for (int mt = 0; mt < 2; ++mt)
#pragma unroll
    for (int j = 0; j < 2; ++j)
#pragma unroll
      for (int r = 0; r < 4; ++r) {
        int col = (wave * 2 + j) * 16 + lr;
        int rowl = mt * 16 + lg * 4 + r;
        size_t gr = (size_t)blockIdx.x * 32 + rowl;
        int b = (int)(gr >= SQ);
        int pos = (int)gr - b * SQ;
        float qv = (dQ[mt][j][r] + bq[col]) * 0.17677669529663687f;  // Dh^-0.5
        qbf[(((size_t)b * NH + (col >> 5)) * SQ + pos) * DH + (col & 31)] = f2bf(qv);
        gate[gr * 128 + col] = sigm(dG[mt][j][r]);
        zc[gr * 128 + col] = sigm(dZ[mt][j][r] + bzc[col]);
      }
}

__global__ __launch_bounds__(256) void rowblock_k(
    const float* __restrict__ x, const float* __restrict__ cond,
    const float* __restrict__ gamma, const float* __restrict__ bs,
    const u16* __restrict__ WT,
    u16* __restrict__ kbf, u16* __restrict__ vT) {
  __shared__ float xnf[32 * 132];
  __shared__ u16 a_cn[32 * 136];
  __shared__ u16 a_xa[32 * 136];
  const int tid = threadIdx.x;
  const int rl = tid >> 3, sub = tid & 7, c0 = sub * 16;
  const size_t grow = (size_t)blockIdx.x * 32 + rl;
  {
    float xs[16];
    const float4* xr = reinterpret_cast<const float4*>(x + grow * 128 + c0);
#pragma unroll
    for (int i = 0; i < 4; ++i) { float4 t = xr[i]; xs[4*i]=t.x; xs[4*i+1]=t.y; xs[4*i+2]=t.z; xs[4*i+3]=t.w; }
    float s = 0.f;
#pragma unroll
    for (int i = 0; i < 16; ++i) s += xs[i];
    float mean = red8(s) * (1.f / 128.f);
    float vs = 0.f;
#pragma unroll
    for (int i = 0; i < 16; ++i) { float dd = xs[i] - mean; vs += dd * dd; }
    float rstd = rsqrtf(red8(vs) * (1.f / 128.f) + 1e-5f);
    float4* xw = reinterpret_cast<float4*>(&xnf[rl * 132 + c0]);
#pragma unroll
    for (int i = 0; i < 4; ++i) {
      float4 t;
      t.x = (xs[4*i+0] - mean) * rstd; t.y = (xs[4*i+1] - mean) * rstd;
      t.z = (xs[4*i+2] - mean) * rstd; t.w = (xs[4*i+3] - mean) * rstd;
      xw[i] = t;
    }
  }
  {
    float cs[16], gs[16];
    const float4* cr = reinterpret_cast<const float4*>(cond + grow * 128 + c0);
    const float4* gr = reinterpret_cast<const float4*>(gamma + c0);
#pragma unroll
    for (int i = 0; i < 4; ++i) { float4 t = cr[i]; cs[4*i]=t.x; cs[4*i+1]=t.y; cs[4*i+2]=t.z; cs[4*i+3]=t.w; }
#pragma unroll
    for (int i = 0; i < 4; ++i) { float4 t = gr[i]; gs[4*i]=t.x; gs[4*i+1]=t.y; gs[4*i+2]=t.z; gs[4*i+3]=t.w; }
    float s = 0.f;
#pragma unroll
    for (int i = 0; i < 16; ++i) s += cs[i];
    float mean = red8(s) * (1.f / 128.f);
    float vs = 0.f;
#pragma unroll
    for (int i = 0; i < 16; ++i) { float dd = cs[i] - mean; vs += dd * dd; }
    float rstd = rsqrtf(red8(vs) * (1.f / 128.f) + 1e-5f);
    float cn[16];
#pragma unroll
    for (int i = 0; i < 16; ++i) cn[i] = (cs[i] - mean) * rstd * gs[i];
    u32x4* cw = reinterpret_cast<u32x4*>(&a_cn[rl * 136 + c0]);
    u32x4 w0 = {pk2(cn[0],cn[1]), pk2(cn[2],cn[3]), pk2(cn[4],cn[5]), pk2(cn[6],cn[7])};
    u32x4 w1 = {pk2(cn[8],cn[9]), pk2(cn[10],cn[11]), pk2(cn[12],cn[13]), pk2(cn[14],cn[15])};
    cw[0] = w0; cw[1] = w1;
  }
  __syncthreads();
  const int lane = tid & 63, wave = tid >> 6, lr = lane & 15, lg = lane >> 4;
  f32x4 dS[2][2], dB[2][2];
  gemm32x128(a_cn, WT + 5 * 16384, lr, lg, wave, dS);
  gemm32x128(a_cn, WT + 6 * 16384, lr, lg, wave, dB);
#pragma unroll
  for (int mt = 0; mt < 2; ++mt)
#pragma unroll
    for (int j = 0; j < 2; ++j)
#pragma unroll
      for (int r = 0; r < 4; ++r) {
        int col = (wave * 2 + j) * 16 + lr;
        int rowl = mt * 16 + lg * 4 + r;
        float sc = dS[mt][j][r] + bs[col];
        float xa = sigm(sc) * xnf[rowl * 132 + col] + dB[mt][j][r];
        a_xa[rowl * 136 + col] = f2bf(xa);
      }
  __syncthreads();
  f32x4 dK[2][2], dV[2][2];
  gemm32x128(a_xa, WT + 7 * 16384, lr, lg, wave, dK);
  gemm32x128(a_xa, WT + 8 * 16384, lr, lg, wave, dV);
#pragma unroll
  for (int mt = 0; mt < 2; ++mt)
#pragma unroll
    for (int j = 0; j < 2; ++j)
#pragma unroll
      for (int r = 0; r < 4; ++r) {
        int col = (wave * 2 + j) * 16 + lr;
        int rowl = mt * 16 + lg * 4 + r;
        size_t gr = (size_t)blockIdx.x * 32 + rowl;
        int b = (int)(gr >= SQ);
        int pos = (int)gr - b * SQ;
        int h = col >> 5, dd = col & 31;
        kbf[(((size_t)b * NH + h) * SQ + pos) * DH + dd] = f2bf(dK[mt][j][r]);
        vT[(((size_t)b * NH + h) * DH + dd) * SQ + pos] = f2bf(dV[mt][j][r]);
      }
}

// Flash attention (round-5 structure) with REP=3 internal repeat for rocprof
// visibility: each rep re-inits m/l/o and recomputes identical wa values
// (deterministic). attn dispatch ~3x duration -> lands in top-5 WITH counters.
#define REP 3
__global__ __launch_bounds__(256) void attn(
    const u16* __restrict__ qbf, const u16* __restrict__ kbf, const u16* __restrict__ vT,
    const float* __restrict__ pair, const int* __restrict__ mask_q,
    const int* __restrict__ mask_k, const float* __restrict__ gate,
    u16* __restrict__ wa) {
  __shared__ float pbuf[2][16][260];   // pair tile dbuf (stride 260: 2-way banks)
  __shared__ u16 plds[4][16 * 72];     // per-wave P tile
  __shared__ float mb[4][16][34];      // merge: o[0..31], m[32], l[33]
  const int tid = threadIdx.x, lane = tid & 63, w = tid >> 6, lr = lane & 15, lg = lane >> 4;
  const int bid = blockIdx.x;
  const int bh = bid & 7, qt = bid >> 3;  // bh in low bits -> XCD pinning
  const int b = bh >> 2, h = bh & 3;
  const int q0 = qt * 16;
  const bf16x8 aq = ld8(qbf + ((size_t)bh * SQ + q0 + lr) * DH + lg * 8);
  float mqm1[4];
#pragma unroll
  for (int r = 0; r < 4; ++r)
    mqm1[r] = 1e9f * ((float)mask_q[b * SQ + q0 + lg * 4 + r] - 1.f);
  const float* prow0 = pair + ((size_t)bh * SQ + q0 + w * 4) * SQ;
  float* pwf = nullptr;
  u16* pw = plds[w];
  for (int rep = 0; rep < REP; ++rep) {
    float m[4], l[4];
#pragma unroll
    for (int r = 0; r < 4; ++r) { m[r] = -1e30f; l[r] = 0.f; }
    const f32x4 zero = {0.f, 0.f, 0.f, 0.f};
    f32x4 o[2]; o[0] = zero; o[1] = zero;
    f32x4 pf[4];
#pragma unroll
    for (int j = 0; j < 4; ++j)
      pf[j] = __builtin_nontemporal_load(
          reinterpret_cast<const f32x4*>(prow0 + (size_t)j * SQ + lane * 4));
    for (int t = 0; t < 12; ++t) {
      const int bsel = t & 1;
#pragma unroll
      for (int j = 0; j < 4; ++j)
        *reinterpret_cast<f32x4*>(&pbuf[bsel][w * 4 + j][lane * 4]) = pf[j];
      __syncthreads();  // tile t visible to all waves (drains vmcnt)
      if (t < 11) {
#pragma unroll
        for (int j = 0; j < 4; ++j)
          pf[j] = __builtin_nontemporal_load(
              reinterpret_cast<const f32x4*>(prow0 + (size_t)j * SQ + (t + 1) * 256 + lane * 4));
      }
      const int kb = t * 256 + w * 64;  // this wave's 64-key chunk
      f32x4 s[4];
#pragma unroll
      for (int kt = 0; kt < 4; ++kt)
        s[kt] = mfma16(aq, ld8(kbf + ((size_t)bh * SQ + kb + kt * 16 + lr) * DH + lg * 8), zero);
      float mk1[4];
#pragma unroll
      for (int kt = 0; kt < 4; ++kt)
        mk1[kt] = (float)mask_k[b * SQ + kb + kt * 16 + lr] - 1.f;
#pragma unroll
      for (int kt = 0; kt < 4; ++kt)
#pragma unroll
        for (int r = 0; r < 4; ++r) {
          float pv = pbuf[bsel][lg * 4 + r][w * 64 + kt * 16 + lr];
          s[kt][r] += fmaf(mqm1[r], mk1[kt], pv);  // exact-1e9 masking preserved
        }
      float alpha[4];
#pragma unroll
      for (int r = 0; r < 4; ++r) {
        float mx = fmaxf(fmaxf(s[0][r], s[1][r]), fmaxf(s[2][r], s[3][r]));
        mx = fmaxf(mx, __shfl_xor(mx, 1));
        mx = fmaxf(mx, __shfl_xor(mx, 2));
        mx = fmaxf(mx, __shfl_xor(mx, 4));
        mx = fmaxf(mx, __shfl_xor(mx, 8));
        float mn = fmaxf(m[r], mx);
        alpha[r] = __expf(m[r] - mn);
        m[r] = mn;
      }
#pragma unroll
      for (int r = 0; r < 4; ++r) {
        float acc = 0.f;
#pragma unroll
        for (int kt = 0; kt < 4; ++kt) {
          float p = __expf(s[kt][r] - m[r]);
          s[kt][r] = p;
          acc += p;
        }
        acc += __shfl_xor(acc, 1); acc += __shfl_xor(acc, 2);
        acc += __shfl_xor(acc, 4); acc += __shfl_xor(acc, 8);
        l[r] = l[r] * alpha[r] + acc;
        o[0][r] *= alpha[r];
        o[1][r] *= alpha[r];
      }
#pragma unroll
      for (int kt = 0; kt < 4; ++kt)
#pragma unroll
        for (int r = 0; r < 4; ++r)
          pw[(lg * 4 + r) * 72 + kt * 16 + lr] = f2bf(s[kt][r]);
#pragma unroll
      for (int kc = 0; kc < 2; ++kc) {
        bf16x8 pa = ld8(pw + lr * 72 + kc * 32 + lg * 8);
#pragma unroll
        for (int hf = 0; hf < 2; ++hf) {
          bf16x8 bv = ld8(vT + ((size_t)bh * DH + hf * 16 + lr) * SQ + kb + kc * 32 + lg * 8);
          o[hf] = mfma16(pa, bv, o[hf]);
        }
      }
    }
    // block merge of 4 wave-partials
#pragma unroll
    for (int r = 0; r < 4; ++r) {
      int row = lg * 4 + r;
      mb[w][row][lr] = o[0][r];
      mb[w][row][16 + lr] = o[1][r];
      if (lr == 0) { mb[w][row][32] = m[r]; mb[w][row][33] = l[r]; }
    }
    __syncthreads();
#pragma unroll
    for (int it = 0; it < 2; ++it) {
      int q = (tid >> 5) + it * 8;  // 0..15
      int d = tid & 31;
      float m0 = mb[0][q][32], m1 = mb[1][q][32], m2 = mb[2][q][32], m3 = mb[3][q][32];
      float mm = fmaxf(fmaxf(m0, m1), fmaxf(m2, m3));
      float ll = 0.f, oo = 0.f;
#pragma unroll
      for (int w4 = 0; w4 < 4; ++w4) {
        float e = __expf(mb[w4][q][32] - mm);
        ll = fmaf(e, mb[w4][q][33], ll);
        oo = fmaf(e, mb[w4][q][d], oo);
      }
      size_t gi = ((size_t)b * SQ + q0 + q) * 128 + h * 32 + d;
      wa[gi] = f2bf((oo / ll) * gate[gi]);
    }
    __syncthreads();  // separate reps (mb reuse)
  }
  (void)pwf;
}

// out = (wa @ Wt2) * zc
__global__ __launch_bounds__(256) void finalk(
    const u16* __restrict__ wa, const u16* __restrict__ WTt2,
    const float* __restrict__ zc, float* __restrict__ out) {
  __shared__ u16 awa[32 * 136];
  const int tid = threadIdx.x, rl = tid >> 3, sub = tid & 7, c0 = sub * 16;
  const size_t grow = (size_t)blockIdx.x * 32 + rl;
  const u32x4* srcp = reinterpret_cast<const u32x4*>(wa + grow * 128 + c0);
  u32x4* dstp = reinterpret_cast<u32x4*>(&awa[rl * 136 + c0]);
  dstp[0] = srcp[0];
  dstp[1] = srcp[1];
  __syncthreads();
  const int lane = tid & 63, wave = tid >> 6, lr = lane & 15, lg = lane >> 4;
  f32x4 d[2][2];
  gemm32x128(awa, WTt2, lr, lg, wave, d);
#pragma unroll
  for (int mt = 0; mt < 2; ++mt)
#pragma unroll
    for (int j = 0; j < 2; ++j)
#pragma unroll
      for (int r = 0; r < 4; ++r) {
        int col = (wave * 2 + j) * 16 + lr;
        size_t gr = (size_t)blockIdx.x * 32 + mt * 16 + lg * 4 + r;
        out[gr * 128 + col] = d[mt][j][r] * zc[gr * 128 + col];
      }
}

extern "C" void kernel_launch(void* const* d_in, const int* in_sizes, int n_in,
                              void* d_out, int out_size, void* d_ws, size_t ws_size,
                              hipStream_t stream) {
  const float* x_q   = (const float*)d_in[0];
  const float* x_k   = (const float*)d_in[1];
  const int* mask_q  = (const int*)d_in[2];
  const int* mask_k  = (const int*)d_in[3];
  const float* pair  = (const float*)d_in[4];
  const float* scq   = (const float*)d_in[5];
  const float* sck   = (const float*)d_in[6];
  const float* gamma_cq = (const float*)d_in[7];
  const float* Wsq   = (const float*)d_in[8];
  const float* bsq   = (const float*)d_in[9];
  const float* Wbq   = (const float*)d_in[10];
  const float* gamma_ck = (const float*)d_in[11];
  const float* Wsk   = (const float*)d_in[12];
  const float* bsk   = (const float*)d_in[13];
  const float* Wbk   = (const float*)d_in[14];
  const float* Wq    = (const float*)d_in[15];
  const float* bq    = (const float*)d_in[16];
  const float* Wk    = (const float*)d_in[17];
  const float* Wv    = (const float*)d_in[18];
  const float* Wg    = (const float*)d_in[19];
  const float* Wt2   = (const float*)d_in[20];
  const float* Wzc   = (const float*)d_in[21];
  const float* bzc   = (const float*)d_in[22];

  char* wsb = (char*)d_ws;
  u16* WT     = (u16*)(wsb);                 // 10 x 32KB transposed bf16 weights
  u16* qbf    = (u16*)(wsb + 327680);        // [B,H,S,DH] bf16
  u16* kbf    = (u16*)(wsb + 1900544);       // [B,H,S,DH] bf16
  u16* vT     = (u16*)(wsb + 3473408);       // [B,H,DH,S] bf16
  float* gate = (float*)(wsb + 5046272);     // [B,S,C] f32
  float* zc   = (float*)(wsb + 8192000);     // [B,S,C] f32
  u16* wa     = (u16*)(wsb + 11337728);      // [B,S,C] bf16
  float* out  = (float*)d_out;

  PrepSrc ps;
  ps.p[0] = Wsq; ps.p[1] = Wbq; ps.p[2] = Wq; ps.p[3] = Wg; ps.p[4] = Wzc;
  ps.p[5] = Wsk; ps.p[6] = Wbk; ps.p[7] = Wk; ps.p[8] = Wv; ps.p[9] = Wt2;

  hipLaunchKernelGGL(prep, dim3(640), dim3(256), 0, stream, ps, WT);
  hipLaunchKernelGGL(rowblock_q, dim3(192), dim3(256), 0, stream,
                     x_q, scq, gamma_cq, bsq, bq, bzc, WT, qbf, gate, zc);
  hipLaunchKernelGGL(rowblock_k, dim3(192), dim3(256), 0, stream,
                     x_k, sck, gamma_ck, bsk, WT, kbf, vT);
  // PROFILING ROUND: attn has REP=3 internal repeat (identical output) so its
  // dispatch exceeds the harness fills and surfaces in rocprof top-5.
  hipLaunchKernelGGL(attn, dim3(8 * 192), dim3(256), 0, stream,
                     qbf, kbf, vT, pair, mask_q, mask_k, gate, wa);
  hipLaunchKernelGGL(finalk, dim3(192), dim3(256), 0, stream, wa, WT + 9 * 16384, zc, out);
}

// Round 10
// 142.127 us; speedup vs baseline: 2.0378x; 2.0378x over previous
//
#include <hip/hip_runtime.h>
#include <hip/hip_bf16.h>

typedef unsigned short u16;
typedef unsigned int u32;
typedef __attribute__((ext_vector_type(4))) float f32x4;
typedef __attribute__((ext_vector_type(4))) u32 u32x4;
typedef __attribute__((ext_vector_type(2))) u32 u32x2;
typedef __attribute__((ext_vector_type(8))) __bf16 bf16x8;

#define SQ 3072
#define NH 4
#define DH 32

static __device__ __forceinline__ u16 f2bf(float f) {
  return __builtin_bit_cast(u16, (__bf16)f);
}
static __device__ __forceinline__ u32 pk2(float a, float b) {
  return (u32)f2bf(a) | ((u32)f2bf(b) << 16);
}
static __device__ __forceinline__ bf16x8 ld8(const u16* p) {
  return __builtin_bit_cast(bf16x8, *reinterpret_cast<const u32x4*>(p));
}
static __device__ __forceinline__ f32x4 mfma16(bf16x8 a, bf16x8 b, f32x4 c) {
  return __builtin_amdgcn_mfma_f32_16x16x32_bf16(a, b, c, 0, 0, 0);
}
static __device__ __forceinline__ float sigm(float x) { return 1.0f / (1.0f + __expf(-x)); }
static __device__ __forceinline__ float red8(float v) {
  v += __shfl_xor(v, 1); v += __shfl_xor(v, 2); v += __shfl_xor(v, 4);
  return v;
}

// A: 32x128 bf16 in LDS (row stride 136). B: WT[cout][k] bf16 (128x128, row stride 128).
static __device__ __forceinline__ void gemm32x128(
    const u16* a, const u16* wt, int lr, int lg, int wave, f32x4 d[2][2]) {
  f32x4 z = {0.f, 0.f, 0.f, 0.f};
  d[0][0] = z; d[0][1] = z; d[1][0] = z; d[1][1] = z;
#pragma unroll
  for (int kc = 0; kc < 4; ++kc) {
    int ko = kc * 32 + lg * 8;
    bf16x8 a0 = ld8(a + lr * 136 + ko);
    bf16x8 a1 = ld8(a + (16 + lr) * 136 + ko);
    bf16x8 b0 = ld8(wt + ((wave * 2 + 0) * 16 + lr) * 128 + ko);
    bf16x8 b1 = ld8(wt + ((wave * 2 + 1) * 16 + lr) * 128 + ko);
    d[0][0] = mfma16(a0, b0, d[0][0]);
    d[1][0] = mfma16(a1, b0, d[1][0]);
    d[0][1] = mfma16(a0, b1, d[0][1]);
    d[1][1] = mfma16(a1, b1, d[1][1]);
  }
}

struct PrepSrc { const float* p[10]; };

// Coalesced transpose: dst[m][cout][k] = W_m[k][cout], via LDS tile.
__global__ __launch_bounds__(256) void prep(PrepSrc s, u16* __restrict__ dst) {
  __shared__ float tl[32][132];
  const int mm = blockIdx.x >> 2, c = blockIdx.x & 3;
  const int tid = threadIdx.x;
  {
    const int krl = tid >> 3, col0 = (tid & 7) * 16;
    const int kr = c * 32 + krl;
    const float* src = s.p[mm] + kr * 128 + col0;
#pragma unroll
    for (int j = 0; j < 4; ++j) {
      f32x4 v = *reinterpret_cast<const f32x4*>(src + j * 4);
      tl[krl][col0 + j * 4 + 0] = v[0];
      tl[krl][col0 + j * 4 + 1] = v[1];
      tl[krl][col0 + j * 4 + 2] = v[2];
      tl[krl][col0 + j * 4 + 3] = v[3];
    }
  }
  __syncthreads();
  const int co = tid >> 1, kc0 = (tid & 1) * 16;
  u32 wbuf[8];
#pragma unroll
  for (int j = 0; j < 8; ++j)
    wbuf[j] = pk2(tl[kc0 + 2 * j][co], tl[kc0 + 2 * j + 1][co]);
  u32x4* dp = reinterpret_cast<u32x4*>(dst + mm * 16384 + co * 128 + c * 32 + kc0);
  u32x4 w0 = {wbuf[0], wbuf[1], wbuf[2], wbuf[3]};
  u32x4 w1 = {wbuf[4], wbuf[5], wbuf[6], wbuf[7]};
  dp[0] = w0; dp[1] = w1;
}

__global__ __launch_bounds__(256) void rowblock_q(
    const float* __restrict__ x, const float* __restrict__ cond,
    const float* __restrict__ gamma, const float* __restrict__ bs,
    const float* __restrict__ bq, const float* __restrict__ bzc,
    const u16* __restrict__ WT,
    u16* __restrict__ qbf, float* __restrict__ gate, float* __restrict__ zc) {
  __shared__ float xnf[32 * 132];
  __shared__ u16 a_cn[32 * 136];
  __shared__ u16 a_raw[32 * 136];
  __shared__ u16 a_xa[32 * 136];
  const int tid = threadIdx.x;
  const int rl = tid >> 3, sub = tid & 7, c0 = sub * 16;
  const size_t grow = (size_t)blockIdx.x * 32 + rl;

  {
    float xs[16];
    const float4* xr = reinterpret_cast<const float4*>(x + grow * 128 + c0);
#pragma unroll
    for (int i = 0; i < 4; ++i) { float4 t = xr[i]; xs[4*i]=t.x; xs[4*i+1]=t.y; xs[4*i+2]=t.z; xs[4*i+3]=t.w; }
    float s = 0.f;
#pragma unroll
    for (int i = 0; i < 16; ++i) s += xs[i];
    float mean = red8(s) * (1.f / 128.f);
    float vs = 0.f;
#pragma unroll
    for (int i = 0; i < 16; ++i) { float dd = xs[i] - mean; vs += dd * dd; }
    float rstd = rsqrtf(red8(vs) * (1.f / 128.f) + 1e-5f);
    float4* xw = reinterpret_cast<float4*>(&xnf[rl * 132 + c0]);
#pragma unroll
    for (int i = 0; i < 4; ++i) {
      float4 t;
      t.x = (xs[4*i+0] - mean) * rstd; t.y = (xs[4*i+1] - mean) * rstd;
      t.z = (xs[4*i+2] - mean) * rstd; t.w = (xs[4*i+3] - mean) * rstd;
      xw[i] = t;
    }
  }
  {
    float cs[16], gs[16];
    const float4* cr = reinterpret_cast<const float4*>(cond + grow * 128 + c0);
    const float4* gr = reinterpret_cast<const float4*>(gamma + c0);
#pragma unroll
    for (int i = 0; i < 4; ++i) { float4 t = cr[i]; cs[4*i]=t.x; cs[4*i+1]=t.y; cs[4*i+2]=t.z; cs[4*i+3]=t.w; }
#pragma unroll
    for (int i = 0; i < 4; ++i) { float4 t = gr[i]; gs[4*i]=t.x; gs[4*i+1]=t.y; gs[4*i+2]=t.z; gs[4*i+3]=t.w; }
    float s = 0.f;
#pragma unroll
    for (int i = 0; i < 16; ++i) s += cs[i];
    float mean = red8(s) * (1.f / 128.f);
    float vs = 0.f;
#pragma unroll
    for (int i = 0; i < 16; ++i) { float dd = cs[i] - mean; vs += dd * dd; }
    float rstd = rsqrtf(red8(vs) * (1.f / 128.f) + 1e-5f);
    float cn[16];
#pragma unroll
    for (int i = 0; i < 16; ++i) cn[i] = (cs[i] - mean) * rstd * gs[i];
    u32x4* cw = reinterpret_cast<u32x4*>(&a_cn[rl * 136 + c0]);
    u32x4 w0 = {pk2(cn[0],cn[1]), pk2(cn[2],cn[3]), pk2(cn[4],cn[5]), pk2(cn[6],cn[7])};
    u32x4 w1 = {pk2(cn[8],cn[9]), pk2(cn[10],cn[11]), pk2(cn[12],cn[13]), pk2(cn[14],cn[15])};
    cw[0] = w0; cw[1] = w1;
    u32x4* rw = reinterpret_cast<u32x4*>(&a_raw[rl * 136 + c0]);
    u32x4 r0 = {pk2(cs[0],cs[1]), pk2(cs[2],cs[3]), pk2(cs[4],cs[5]), pk2(cs[6],cs[7])};
    u32x4 r1 = {pk2(cs[8],cs[9]), pk2(cs[10],cs[11]), pk2(cs[12],cs[13]), pk2(cs[14],cs[15])};
    rw[0] = r0; rw[1] = r1;
  }
  __syncthreads();
  const int lane = tid & 63, wave = tid >> 6, lr = lane & 15, lg = lane >> 4;
  f32x4 dS[2][2], dB[2][2];
  gemm32x128(a_cn, WT + 0 * 16384, lr, lg, wave, dS);
  gemm32x128(a_cn, WT + 1 * 16384, lr, lg, wave, dB);
#pragma unroll
  for (int mt = 0; mt < 2; ++mt)
#pragma unroll
    for (int j = 0; j < 2; ++j)
#pragma unroll
      for (int r = 0; r < 4; ++r) {
        int col = (wave * 2 + j) * 16 + lr;
        int rowl = mt * 16 + lg * 4 + r;
        float sc = dS[mt][j][r] + bs[col];
        float xa = sigm(sc) * xnf[rowl * 132 + col] + dB[mt][j][r];
        a_xa[rowl * 136 + col] = f2bf(xa);
      }
  __syncthreads();
  f32x4 dQ[2][2], dG[2][2], dZ[2][2];
  gemm32x128(a_xa, WT + 2 * 16384, lr, lg, wave, dQ);
  gemm32x128(a_xa, WT + 3 * 16384, lr, lg, wave, dG);
  gemm32x128(a_raw, WT + 4 * 16384, lr, lg, wave, dZ);
#pragma unroll
  for (int mt = 0; mt < 2; ++mt)
#pragma unroll
    for (int j = 0; j < 2; ++j)
#pragma unroll
      for (int r = 0; r < 4; ++r) {
        int col = (wave * 2 + j) * 16 + lr;
        int rowl = mt * 16 + lg * 4 + r;
        size_t gr = (size_t)blockIdx.x * 32 + rowl;
        int b = (int)(gr >= SQ);
        int pos = (int)gr - b * SQ;
        float qv = (dQ[mt][j][r] + bq[col]) * 0.17677669529663687f;  // Dh^-0.5
        qbf[(((size_t)b * NH + (col >> 5)) * SQ + pos) * DH + (col & 31)] = f2bf(qv);
        gate[gr * 128 + col] = sigm(dG[mt][j][r]);
        zc[gr * 128 + col] = sigm(dZ[mt][j][r] + bzc[col]);
      }
}

__global__ __launch_bounds__(256) void rowblock_k(
    const float* __restrict__ x, const float* __restrict__ cond,
    const float* __restrict__ gamma, const float* __restrict__ bs,
    const u16* __restrict__ WT, const int* __restrict__ mask_k,
    u16* __restrict__ kbf, u16* __restrict__ vT, float* __restrict__ mkf) {
  __shared__ float xnf[32 * 132];
  __shared__ u16 a_cn[32 * 136];
  __shared__ u16 a_xa[32 * 136];
  const int tid = threadIdx.x;
  const int rl = tid >> 3, sub = tid & 7, c0 = sub * 16;
  const size_t grow = (size_t)blockIdx.x * 32 + rl;
  if (tid < 32) {
    size_t g2 = (size_t)blockIdx.x * 32 + tid;
    mkf[g2] = (float)mask_k[g2] - 1.f;
  }
  {
    float xs[16];
    const float4* xr = reinterpret_cast<const float4*>(x + grow * 128 + c0);
#pragma unroll
    for (int i = 0; i < 4; ++i) { float4 t = xr[i]; xs[4*i]=t.x; xs[4*i+1]=t.y; xs[4*i+2]=t.z; xs[4*i+3]=t.w; }
    float s = 0.f;
#pragma unroll
    for (int i = 0; i < 16; ++i) s += xs[i];
    float mean = red8(s) * (1.f / 128.f);
    float vs = 0.f;
#pragma unroll
    for (int i = 0; i < 16; ++i) { float dd = xs[i] - mean; vs += dd * dd; }
    float rstd = rsqrtf(red8(vs) * (1.f / 128.f) + 1e-5f);
    float4* xw = reinterpret_cast<float4*>(&xnf[rl * 132 + c0]);
#pragma unroll
    for (int i = 0; i < 4; ++i) {
      float4 t;
      t.x = (xs[4*i+0] - mean) * rstd; t.y = (xs[4*i+1] - mean) * rstd;
      t.z = (xs[4*i+2] - mean) * rstd; t.w = (xs[4*i+3] - mean) * rstd;
      xw[i] = t;
    }
  }
  {
    float cs[16], gs[16];
    const float4* cr = reinterpret_cast<const float4*>(cond + grow * 128 + c0);
    const float4* gr = reinterpret_cast<const float4*>(gamma + c0);
#pragma unroll
    for (int i = 0; i < 4; ++i) { float4 t = cr[i]; cs[4*i]=t.x; cs[4*i+1]=t.y; cs[4*i+2]=t.z; cs[4*i+3]=t.w; }
#pragma unroll
    for (int i = 0; i < 4; ++i) { float4 t = gr[i]; gs[4*i]=t.x; gs[4*i+1]=t.y; gs[4*i+2]=t.z; gs[4*i+3]=t.w; }
    float s = 0.f;
#pragma unroll
    for (int i = 0; i < 16; ++i) s += cs[i];
    float mean = red8(s) * (1.f / 128.f);
    float vs = 0.f;
#pragma unroll
    for (int i = 0; i < 16; ++i) { float dd = cs[i] - mean; vs += dd * dd; }
    float rstd = rsqrtf(red8(vs) * (1.f / 128.f) + 1e-5f);
    float cn[16];
#pragma unroll
    for (int i = 0; i < 16; ++i) cn[i] = (cs[i] - mean) * rstd * gs[i];
    u32x4* cw = reinterpret_cast<u32x4*>(&a_cn[rl * 136 + c0]);
    u32x4 w0 = {pk2(cn[0],cn[1]), pk2(cn[2],cn[3]), pk2(cn[4],cn[5]), pk2(cn[6],cn[7])};
    u32x4 w1 = {pk2(cn[8],cn[9]), pk2(cn[10],cn[11]), pk2(cn[12],cn[13]), pk2(cn[14],cn[15])};
    cw[0] = w0; cw[1] = w1;
  }
  __syncthreads();
  const int lane = tid & 63, wave = tid >> 6, lr = lane & 15, lg = lane >> 4;
  f32x4 dS[2][2], dB[2][2];
  gemm32x128(a_cn, WT + 5 * 16384, lr, lg, wave, dS);
  gemm32x128(a_cn, WT + 6 * 16384, lr, lg, wave, dB);
#pragma unroll
  for (int mt = 0; mt < 2; ++mt)
#pragma unroll
    for (int j = 0; j < 2; ++j)
#pragma unroll
      for (int r = 0; r < 4; ++r) {
        int col = (wave * 2 + j) * 16 + lr;
        int rowl = mt * 16 + lg * 4 + r;
        float sc = dS[mt][j][r] + bs[col];
        float xa = sigm(sc) * xnf[rowl * 132 + col] + dB[mt][j][r];
        a_xa[rowl * 136 + col] = f2bf(xa);
      }
  __syncthreads();
  f32x4 dK[2][2], dV[2][2];
  gemm32x128(a_xa, WT + 7 * 16384, lr, lg, wave, dK);
  gemm32x128(a_xa, WT + 8 * 16384, lr, lg, wave, dV);
#pragma unroll
  for (int mt = 0; mt < 2; ++mt)
#pragma unroll
    for (int j = 0; j < 2; ++j)
#pragma unroll
      for (int r = 0; r < 4; ++r) {
        int col = (wave * 2 + j) * 16 + lr;
        int rowl = mt * 16 + lg * 4 + r;
        size_t gr = (size_t)blockIdx.x * 32 + rowl;
        int b = (int)(gr >= SQ);
        int pos = (int)gr - b * SQ;
        int h = col >> 5, dd = col & 31;
        kbf[(((size_t)b * NH + h) * SQ + pos) * DH + dd] = f2bf(dK[mt][j][r]);
        vT[(((size_t)b * NH + h) * DH + dd) * SQ + pos] = f2bf(dV[mt][j][r]);
      }
}

// Flash attention v10: R8's verified swapped-operand layout + defer-max (THR=8)
// + 2-tile (128k) ILP + packed P-stores. Latency-bound fix: the serial online-max
// chain is skipped on the common path, so the two 64k softmax chains and the
// next iteration's loads all overlap. No barriers; wave-private LDS only.
__global__ __launch_bounds__(256) void attn(
    const u16* __restrict__ qbf, const u16* __restrict__ kbf, const u16* __restrict__ vT,
    const float* __restrict__ pair, const int* __restrict__ mask_q,
    const float* __restrict__ mkf,
    float* __restrict__ part_o, float* __restrict__ part_m, float* __restrict__ part_l) {
  __shared__ u16 plds[4][2][16 * 72];
  const int tid = threadIdx.x, lane = tid & 63, w = tid >> 6, lr = lane & 15, lg = lane >> 4;
  const int bid = blockIdx.x;
  const int bh = bid & 7;              // XCD spread
  const int rest = bid >> 3;           // 0..95
  const int z = rest & 1, qtb = rest >> 1;
  const int b = bh >> 2;
  const int q0 = qtb * 64 + w * 16;
  const int k0 = z * 1536;
  const bf16x8 aq = ld8(qbf + ((size_t)bh * SQ + q0 + lr) * DH + lg * 8);  // B operand (Q)
  const float mqm1 = 1e9f * ((float)mask_q[b * SQ + q0 + lr] - 1.f);       // per-lane q=lr
  float m = -1e30f, lsum = 0.f;
  const f32x4 zero = {0.f, 0.f, 0.f, 0.f};
  f32x4 o[2]; o[0] = zero; o[1] = zero;
  const float* prow = pair + ((size_t)bh * SQ + q0 + lr) * SQ;  // pair row of q=q0+lr
  const float* mrow = mkf + b * SQ;
  const u16* krow = kbf + (size_t)bh * SQ * DH;
  const u16* vrow = vT + (size_t)bh * DH * SQ;

  f32x4 ca[2][4];   // pair + mask bias, C-fragment layout
  bf16x8 kf[2][4];  // K fragments
  auto pref = [&](int KK) {
#pragma unroll
    for (int tt = 0; tt < 2; ++tt)
#pragma unroll
      for (int kt = 0; kt < 4; ++kt) {
        const int kk = KK + tt * 64 + kt * 16;
        f32x4 pv = __builtin_nontemporal_load(
            reinterpret_cast<const f32x4*>(prow + kk + lg * 4));
        f32x4 mk = *reinterpret_cast<const f32x4*>(mrow + kk + lg * 4);
        f32x4 c;
        c[0] = fmaf(mqm1, mk[0], pv[0]); c[1] = fmaf(mqm1, mk[1], pv[1]);
        c[2] = fmaf(mqm1, mk[2], pv[2]); c[3] = fmaf(mqm1, mk[3], pv[3]);
        ca[tt][kt] = c;
        kf[tt][kt] = ld8(krow + (size_t)(kk + lr) * DH + lg * 8);
      }
  };
  pref(k0);
  for (int it = 0; it < 12; ++it) {
    const int kb = k0 + it * 128;
    // QK^T: 8 MFMAs, pair+mask folded into C (D[row=k][col=q])
    f32x4 s[2][4];
#pragma unroll
    for (int tt = 0; tt < 2; ++tt)
#pragma unroll
      for (int kt = 0; kt < 4; ++kt)
        s[tt][kt] = mfma16(kf[tt][kt], aq, ca[tt][kt]);
    // prefetch next 128k under this iteration's softmax+PV
    if (it < 11) pref(kb + 128);
    // max over 32 k-values (in-reg tree) + 2 shfl across lane groups
    f32x4 mx = s[0][0];
#pragma unroll
    for (int tt = 0; tt < 2; ++tt)
#pragma unroll
      for (int kt = 0; kt < 4; ++kt)
        if (tt | kt) {
#pragma unroll
          for (int r = 0; r < 4; ++r) mx[r] = fmaxf(mx[r], s[tt][kt][r]);
        }
    float pm = fmaxf(fmaxf(mx[0], mx[1]), fmaxf(mx[2], mx[3]));
    pm = fmaxf(pm, __shfl_xor(pm, 16));
    pm = fmaxf(pm, __shfl_xor(pm, 32));
    // defer-max: common path keeps m (no rescale, no serial dependency)
    if (!__all(pm <= m + 8.f)) {
      const float mn = fmaxf(m, pm);
      const float alpha = __expf(m - mn);
      m = mn;
      float al[4];
#pragma unroll
      for (int r = 0; r < 4; ++r)
        al[r] = __builtin_bit_cast(
            float, __builtin_amdgcn_ds_bpermute((lg * 4 + r) << 2,
                                                __builtin_bit_cast(int, alpha)));
#pragma unroll
      for (int hf = 0; hf < 2; ++hf)
#pragma unroll
        for (int r = 0; r < 4; ++r) o[hf][r] *= al[r];
      lsum *= alpha;
    }
    float ps = 0.f;
#pragma unroll
    for (int tt = 0; tt < 2; ++tt)
#pragma unroll
      for (int kt = 0; kt < 4; ++kt)
#pragma unroll
        for (int r = 0; r < 4; ++r) {
          float p = __expf(s[tt][kt][r] - m);
          s[tt][kt][r] = p;
          ps += p;
        }
    lsum += ps;
    // P pack (4x 8B stores per tile) + PV
#pragma unroll
    for (int tt = 0; tt < 2; ++tt) {
      u16* pw = plds[w][tt];
#pragma unroll
      for (int kt = 0; kt < 4; ++kt) {
        u32x2 pk = {pk2(s[tt][kt][0], s[tt][kt][1]), pk2(s[tt][kt][2], s[tt][kt][3])};
        *reinterpret_cast<u32x2*>(pw + lr * 72 + kt * 16 + lg * 4) = pk;
      }
#pragma unroll
      for (int kc = 0; kc < 2; ++kc) {
        bf16x8 pa = ld8(pw + lr * 72 + kc * 32 + lg * 8);
#pragma unroll
        for (int hf = 0; hf < 2; ++hf) {
          bf16x8 bv = ld8(vrow + (size_t)(hf * 16 + lr) * SQ + kb + tt * 64 + kc * 32 + lg * 8);
          o[hf] = mfma16(pa, bv, o[hf]);
        }
      }
    }
  }
  lsum += __shfl_xor(lsum, 16);
  lsum += __shfl_xor(lsum, 32);
  const int zb = (z * 8 + bh) * SQ;
  if (lane < 16) {
    part_m[zb + q0 + lr] = m;
    part_l[zb + q0 + lr] = lsum;
  }
#pragma unroll
  for (int hf = 0; hf < 2; ++hf)
#pragma unroll
    for (int r = 0; r < 4; ++r)
      part_o[((size_t)(zb + q0 + lg * 4 + r)) * 32 + hf * 16 + lr] = o[hf][r];
}

// finalk: merge 2 k-split partials + gate -> awa (LDS), then (wa @ Wt2) * zc.
__global__ __launch_bounds__(256) void finalk(
    const float* __restrict__ part_o, const float* __restrict__ part_m,
    const float* __restrict__ part_l, const float* __restrict__ gate,
    const u16* __restrict__ WTt2, const float* __restrict__ zc,
    float* __restrict__ out) {
  __shared__ u16 awa[32 * 136];
  const int tid = threadIdx.x, rl = tid >> 3, sub = tid & 7, c0 = sub * 16;
  const int grow = blockIdx.x * 32 + rl;  // [0, 6144)
  const int b = (int)(grow >= SQ), q = grow - b * SQ;
  const int h = sub >> 1, d0 = (sub & 1) * 16;
  const int bh = b * 4 + h;
  const int row0 = bh * SQ + q;
  const int row1 = (8 + bh) * SQ + q;
  const float m0 = part_m[row0], m1 = part_m[row1];
  const float M = fmaxf(m0, m1);
  const float e0 = __expf(m0 - M), e1 = __expf(m1 - M);
  const float inv = 1.f / (e0 * part_l[row0] + e1 * part_l[row1]);
  u32 wb[8];
#pragma unroll
  for (int j4 = 0; j4 < 4; ++j4) {
    f32x4 o0 = *reinterpret_cast<const f32x4*>(part_o + (size_t)row0 * 32 + d0 + j4 * 4);
    f32x4 o1 = *reinterpret_cast<const f32x4*>(part_o + (size_t)row1 * 32 + d0 + j4 * 4);
    f32x4 g  = *reinterpret_cast<const f32x4*>(gate + (size_t)grow * 128 + c0 + j4 * 4);
    float v0 = (e0 * o0[0] + e1 * o1[0]) * inv * g[0];
    float v1 = (e0 * o0[1] + e1 * o1[1]) * inv * g[1];
    float v2 = (e0 * o0[2] + e1 * o1[2]) * inv * g[2];
    float v3 = (e0 * o0[3] + e1 * o1[3]) * inv * g[3];
    wb[j4 * 2 + 0] = pk2(v0, v1);
    wb[j4 * 2 + 1] = pk2(v2, v3);
  }
  u32x4* dstp = reinterpret_cast<u32x4*>(&awa[rl * 136 + c0]);
  u32x4 w0 = {wb[0], wb[1], wb[2], wb[3]};
  u32x4 w1 = {wb[4], wb[5], wb[6], wb[7]};
  dstp[0] = w0; dstp[1] = w1;
  __syncthreads();
  const int lane = tid & 63, wave = tid >> 6, lr = lane & 15, lg = lane >> 4;
  f32x4 d[2][2];
  gemm32x128(awa, WTt2, lr, lg, wave, d);
#pragma unroll
  for (int mt = 0; mt < 2; ++mt)
#pragma unroll
    for (int j = 0; j < 2; ++j)
#pragma unroll
      for (int r = 0; r < 4; ++r) {
        int col = (wave * 2 + j) * 16 + lr;
        size_t gr = (size_t)blockIdx.x * 32 + mt * 16 + lg * 4 + r;
        out[gr * 128 + col] = d[mt][j][r] * zc[gr * 128 + col];
      }
}

extern "C" void kernel_launch(void* const* d_in, const int* in_sizes, int n_in,
                              void* d_out, int out_size, void* d_ws, size_t ws_size,
                              hipStream_t stream) {
  const float* x_q   = (const float*)d_in[0];
  const float* x_k   = (const float*)d_in[1];
  const int* mask_q  = (const int*)d_in[2];
  const int* mask_k  = (const int*)d_in[3];
  const float* pair  = (const float*)d_in[4];
  const float* scq   = (const float*)d_in[5];
  const float* sck   = (const float*)d_in[6];
  const float* gamma_cq = (const float*)d_in[7];
  const float* Wsq   = (const float*)d_in[8];
  const float* bsq   = (const float*)d_in[9];
  const float* Wbq   = (const float*)d_in[10];
  const float* gamma_ck = (const float*)d_in[11];
  const float* Wsk   = (const float*)d_in[12];
  const float* bsk   = (const float*)d_in[13];
  const float* Wbk   = (const float*)d_in[14];
  const float* Wq    = (const float*)d_in[15];
  const float* bq    = (const float*)d_in[16];
  const float* Wk    = (const float*)d_in[17];
  const float* Wv    = (const float*)d_in[18];
  const float* Wg    = (const float*)d_in[19];
  const float* Wt2   = (const float*)d_in[20];
  const float* Wzc   = (const float*)d_in[21];
  const float* bzc   = (const float*)d_in[22];

  char* wsb = (char*)d_ws;
  u16* WT       = (u16*)(wsb);               // 10 x 32KB transposed bf16 weights
  u16* qbf      = (u16*)(wsb + 327680);      // [B,H,S,DH] bf16
  u16* kbf      = (u16*)(wsb + 1900544);     // [B,H,S,DH] bf16
  u16* vT       = (u16*)(wsb + 3473408);     // [B,H,DH,S] bf16
  float* gate   = (float*)(wsb + 5046272);   // [B,S,C] f32
  float* zc     = (float*)(wsb + 8192000);   // [B,S,C] f32
  float* mkf    = (float*)(wsb + 11337728);  // [B,S] f32 mask_k - 1
  float* part_o = (float*)(wsb + 11362304);  // [2,8,SQ,32] f32
  float* part_m = (float*)(wsb + 17653760);  // [2,8,SQ] f32
  float* part_l = (float*)(wsb + 17850368);  // [2,8,SQ] f32
  float* out    = (float*)d_out;

  PrepSrc ps;
  ps.p[0] = Wsq; ps.p[1] = Wbq; ps.p[2] = Wq; ps.p[3] = Wg; ps.p[4] = Wzc;
  ps.p[5] = Wsk; ps.p[6] = Wbk; ps.p[7] = Wk; ps.p[8] = Wv; ps.p[9] = Wt2;

  hipLaunchKernelGGL(prep, dim3(40), dim3(256), 0, stream, ps, WT);
  hipLaunchKernelGGL(rowblock_q, dim3(192), dim3(256), 0, stream,
                     x_q, scq, gamma_cq, bsq, bq, bzc, WT, qbf, gate, zc);
  hipLaunchKernelGGL(rowblock_k, dim3(192), dim3(256), 0, stream,
                     x_k, sck, gamma_ck, bsk, WT, mask_k, kbf, vT, mkf);
  hipLaunchKernelGGL(attn, dim3(768), dim3(256), 0, stream,
                     qbf, kbf, vT, pair, mask_q, mkf, part_o, part_m, part_l);
  hipLaunchKernelGGL(finalk, dim3(192), dim3(256), 0, stream,
                     part_o, part_m, part_l, gate, WT + 9 * 16384, zc, out);
}

// Round 11
// 141.296 us; speedup vs baseline: 2.0498x; 1.0059x over previous
//
#include <hip/hip_runtime.h>
#include <hip/hip_bf16.h>

typedef unsigned short u16;
typedef unsigned int u32;
typedef __attribute__((ext_vector_type(4))) float f32x4;
typedef __attribute__((ext_vector_type(4))) u32 u32x4;
typedef __attribute__((ext_vector_type(2))) u32 u32x2;
typedef __attribute__((ext_vector_type(8))) __bf16 bf16x8;

#define SQ 3072
#define NH 4
#define DH 32

static __device__ __forceinline__ u16 f2bf(float f) {
  return __builtin_bit_cast(u16, (__bf16)f);
}
static __device__ __forceinline__ u32 pk2(float a, float b) {
  return (u32)f2bf(a) | ((u32)f2bf(b) << 16);
}
static __device__ __forceinline__ bf16x8 ld8(const u16* p) {
  return __builtin_bit_cast(bf16x8, *reinterpret_cast<const u32x4*>(p));
}
static __device__ __forceinline__ f32x4 mfma16(bf16x8 a, bf16x8 b, f32x4 c) {
  return __builtin_amdgcn_mfma_f32_16x16x32_bf16(a, b, c, 0, 0, 0);
}
static __device__ __forceinline__ float sigm(float x) { return 1.0f / (1.0f + __expf(-x)); }
static __device__ __forceinline__ float red8(float v) {
  v += __shfl_xor(v, 1); v += __shfl_xor(v, 2); v += __shfl_xor(v, 4);
  return v;
}

// A: 32x128 bf16 in LDS (row stride 136). B: WT[cout][k] bf16 (128x128, row stride 128).
static __device__ __forceinline__ void gemm32x128(
    const u16* a, const u16* wt, int lr, int lg, int wave, f32x4 d[2][2]) {
  f32x4 z = {0.f, 0.f, 0.f, 0.f};
  d[0][0] = z; d[0][1] = z; d[1][0] = z; d[1][1] = z;
#pragma unroll
  for (int kc = 0; kc < 4; ++kc) {
    int ko = kc * 32 + lg * 8;
    bf16x8 a0 = ld8(a + lr * 136 + ko);
    bf16x8 a1 = ld8(a + (16 + lr) * 136 + ko);
    bf16x8 b0 = ld8(wt + ((wave * 2 + 0) * 16 + lr) * 128 + ko);
    bf16x8 b1 = ld8(wt + ((wave * 2 + 1) * 16 + lr) * 128 + ko);
    d[0][0] = mfma16(a0, b0, d[0][0]);
    d[1][0] = mfma16(a1, b0, d[1][0]);
    d[0][1] = mfma16(a0, b1, d[0][1]);
    d[1][1] = mfma16(a1, b1, d[1][1]);
  }
}

struct PrepSrc { const float* p[10]; };

// Coalesced transpose: dst[m][cout][k] = W_m[k][cout], via LDS tile.
__global__ __launch_bounds__(256) void prep(PrepSrc s, u16* __restrict__ dst) {
  __shared__ float tl[32][132];
  const int mm = blockIdx.x >> 2, c = blockIdx.x & 3;
  const int tid = threadIdx.x;
  {
    const int krl = tid >> 3, col0 = (tid & 7) * 16;
    const int kr = c * 32 + krl;
    const float* src = s.p[mm] + kr * 128 + col0;
#pragma unroll
    for (int j = 0; j < 4; ++j) {
      f32x4 v = *reinterpret_cast<const f32x4*>(src + j * 4);
      tl[krl][col0 + j * 4 + 0] = v[0];
      tl[krl][col0 + j * 4 + 1] = v[1];
      tl[krl][col0 + j * 4 + 2] = v[2];
      tl[krl][col0 + j * 4 + 3] = v[3];
    }
  }
  __syncthreads();
  const int co = tid >> 1, kc0 = (tid & 1) * 16;
  u32 wbuf[8];
#pragma unroll
  for (int j = 0; j < 8; ++j)
    wbuf[j] = pk2(tl[kc0 + 2 * j][co], tl[kc0 + 2 * j + 1][co]);
  u32x4* dp = reinterpret_cast<u32x4*>(dst + mm * 16384 + co * 128 + c * 32 + kc0);
  u32x4 w0 = {wbuf[0], wbuf[1], wbuf[2], wbuf[3]};
  u32x4 w1 = {wbuf[4], wbuf[5], wbuf[6], wbuf[7]};
  dp[0] = w0; dp[1] = w1;
}

__global__ __launch_bounds__(256) void rowblock_q(
    const float* __restrict__ x, const float* __restrict__ cond,
    const float* __restrict__ gamma, const float* __restrict__ bs,
    const float* __restrict__ bq, const float* __restrict__ bzc,
    const u16* __restrict__ WT,
    u16* __restrict__ qbf, float* __restrict__ gate, float* __restrict__ zc) {
  __shared__ float xnf[32 * 132];
  __shared__ u16 a_cn[32 * 136];
  __shared__ u16 a_raw[32 * 136];
  __shared__ u16 a_xa[32 * 136];
  const int tid = threadIdx.x;
  const int rl = tid >> 3, sub = tid & 7, c0 = sub * 16;
  const size_t grow = (size_t)blockIdx.x * 32 + rl;

  {
    float xs[16];
    const float4* xr = reinterpret_cast<const float4*>(x + grow * 128 + c0);
#pragma unroll
    for (int i = 0; i < 4; ++i) { float4 t = xr[i]; xs[4*i]=t.x; xs[4*i+1]=t.y; xs[4*i+2]=t.z; xs[4*i+3]=t.w; }
    float s = 0.f;
#pragma unroll
    for (int i = 0; i < 16; ++i) s += xs[i];
    float mean = red8(s) * (1.f / 128.f);
    float vs = 0.f;
#pragma unroll
    for (int i = 0; i < 16; ++i) { float dd = xs[i] - mean; vs += dd * dd; }
    float rstd = rsqrtf(red8(vs) * (1.f / 128.f) + 1e-5f);
    float4* xw = reinterpret_cast<float4*>(&xnf[rl * 132 + c0]);
#pragma unroll
    for (int i = 0; i < 4; ++i) {
      float4 t;
      t.x = (xs[4*i+0] - mean) * rstd; t.y = (xs[4*i+1] - mean) * rstd;
      t.z = (xs[4*i+2] - mean) * rstd; t.w = (xs[4*i+3] - mean) * rstd;
      xw[i] = t;
    }
  }
  {
    float cs[16], gs[16];
    const float4* cr = reinterpret_cast<const float4*>(cond + grow * 128 + c0);
    const float4* gr = reinterpret_cast<const float4*>(gamma + c0);
#pragma unroll
    for (int i = 0; i < 4; ++i) { float4 t = cr[i]; cs[4*i]=t.x; cs[4*i+1]=t.y; cs[4*i+2]=t.z; cs[4*i+3]=t.w; }
#pragma unroll
    for (int i = 0; i < 4; ++i) { float4 t = gr[i]; gs[4*i]=t.x; gs[4*i+1]=t.y; gs[4*i+2]=t.z; gs[4*i+3]=t.w; }
    float s = 0.f;
#pragma unroll
    for (int i = 0; i < 16; ++i) s += cs[i];
    float mean = red8(s) * (1.f / 128.f);
    float vs = 0.f;
#pragma unroll
    for (int i = 0; i < 16; ++i) { float dd = cs[i] - mean; vs += dd * dd; }
    float rstd = rsqrtf(red8(vs) * (1.f / 128.f) + 1e-5f);
    float cn[16];
#pragma unroll
    for (int i = 0; i < 16; ++i) cn[i] = (cs[i] - mean) * rstd * gs[i];
    u32x4* cw = reinterpret_cast<u32x4*>(&a_cn[rl * 136 + c0]);
    u32x4 w0 = {pk2(cn[0],cn[1]), pk2(cn[2],cn[3]), pk2(cn[4],cn[5]), pk2(cn[6],cn[7])};
    u32x4 w1 = {pk2(cn[8],cn[9]), pk2(cn[10],cn[11]), pk2(cn[12],cn[13]), pk2(cn[14],cn[15])};
    cw[0] = w0; cw[1] = w1;
    u32x4* rw = reinterpret_cast<u32x4*>(&a_raw[rl * 136 + c0]);
    u32x4 r0 = {pk2(cs[0],cs[1]), pk2(cs[2],cs[3]), pk2(cs[4],cs[5]), pk2(cs[6],cs[7])};
    u32x4 r1 = {pk2(cs[8],cs[9]), pk2(cs[10],cs[11]), pk2(cs[12],cs[13]), pk2(cs[14],cs[15])};
    rw[0] = r0; rw[1] = r1;
  }
  __syncthreads();
  const int lane = tid & 63, wave = tid >> 6, lr = lane & 15, lg = lane >> 4;
  f32x4 dS[2][2], dB[2][2];
  gemm32x128(a_cn, WT + 0 * 16384, lr, lg, wave, dS);
  gemm32x128(a_cn, WT + 1 * 16384, lr, lg, wave, dB);
#pragma unroll
  for (int mt = 0; mt < 2; ++mt)
#pragma unroll
    for (int j = 0; j < 2; ++j)
#pragma unroll
      for (int r = 0; r < 4; ++r) {
        int col = (wave * 2 + j) * 16 + lr;
        int rowl = mt * 16 + lg * 4 + r;
        float sc = dS[mt][j][r] + bs[col];
        float xa = sigm(sc) * xnf[rowl * 132 + col] + dB[mt][j][r];
        a_xa[rowl * 136 + col] = f2bf(xa);
      }
  __syncthreads();
  f32x4 dQ[2][2], dG[2][2], dZ[2][2];
  gemm32x128(a_xa, WT + 2 * 16384, lr, lg, wave, dQ);
  gemm32x128(a_xa, WT + 3 * 16384, lr, lg, wave, dG);
  gemm32x128(a_raw, WT + 4 * 16384, lr, lg, wave, dZ);
#pragma unroll
  for (int mt = 0; mt < 2; ++mt)
#pragma unroll
    for (int j = 0; j < 2; ++j)
#pragma unroll
      for (int r = 0; r < 4; ++r) {
        int col = (wave * 2 + j) * 16 + lr;
        int rowl = mt * 16 + lg * 4 + r;
        size_t gr = (size_t)blockIdx.x * 32 + rowl;
        int b = (int)(gr >= SQ);
        int pos = (int)gr - b * SQ;
        float qv = (dQ[mt][j][r] + bq[col]) * 0.17677669529663687f;  // Dh^-0.5
        qbf[(((size_t)b * NH + (col >> 5)) * SQ + pos) * DH + (col & 31)] = f2bf(qv);
        gate[gr * 128 + col] = sigm(dG[mt][j][r]);
        zc[gr * 128 + col] = sigm(dZ[mt][j][r] + bzc[col]);
      }
}

__global__ __launch_bounds__(256) void rowblock_k(
    const float* __restrict__ x, const float* __restrict__ cond,
    const float* __restrict__ gamma, const float* __restrict__ bs,
    const u16* __restrict__ WT, const int* __restrict__ mask_k,
    u16* __restrict__ kbf, u16* __restrict__ vT, float* __restrict__ mkf) {
  __shared__ float xnf[32 * 132];
  __shared__ u16 a_cn[32 * 136];
  __shared__ u16 a_xa[32 * 136];
  const int tid = threadIdx.x;
  const int rl = tid >> 3, sub = tid & 7, c0 = sub * 16;
  const size_t grow = (size_t)blockIdx.x * 32 + rl;
  if (tid < 32) {
    size_t g2 = (size_t)blockIdx.x * 32 + tid;
    mkf[g2] = (float)mask_k[g2] - 1.f;
  }
  {
    float xs[16];
    const float4* xr = reinterpret_cast<const float4*>(x + grow * 128 + c0);
#pragma unroll
    for (int i = 0; i < 4; ++i) { float4 t = xr[i]; xs[4*i]=t.x; xs[4*i+1]=t.y; xs[4*i+2]=t.z; xs[4*i+3]=t.w; }
    float s = 0.f;
#pragma unroll
    for (int i = 0; i < 16; ++i) s += xs[i];
    float mean = red8(s) * (1.f / 128.f);
    float vs = 0.f;
#pragma unroll
    for (int i = 0; i < 16; ++i) { float dd = xs[i] - mean; vs += dd * dd; }
    float rstd = rsqrtf(red8(vs) * (1.f / 128.f) + 1e-5f);
    float4* xw = reinterpret_cast<float4*>(&xnf[rl * 132 + c0]);
#pragma unroll
    for (int i = 0; i < 4; ++i) {
      float4 t;
      t.x = (xs[4*i+0] - mean) * rstd; t.y = (xs[4*i+1] - mean) * rstd;
      t.z = (xs[4*i+2] - mean) * rstd; t.w = (xs[4*i+3] - mean) * rstd;
      xw[i] = t;
    }
  }
  {
    float cs[16], gs[16];
    const float4* cr = reinterpret_cast<const float4*>(cond + grow * 128 + c0);
    const float4* gr = reinterpret_cast<const float4*>(gamma + c0);
#pragma unroll
    for (int i = 0; i < 4; ++i) { float4 t = cr[i]; cs[4*i]=t.x; cs[4*i+1]=t.y; cs[4*i+2]=t.z; cs[4*i+3]=t.w; }
#pragma unroll
    for (int i = 0; i < 4; ++i) { float4 t = gr[i]; gs[4*i]=t.x; gs[4*i+1]=t.y; gs[4*i+2]=t.z; gs[4*i+3]=t.w; }
    float s = 0.f;
#pragma unroll
    for (int i = 0; i < 16; ++i) s += cs[i];
    float mean = red8(s) * (1.f / 128.f);
    float vs = 0.f;
#pragma unroll
    for (int i = 0; i < 16; ++i) { float dd = cs[i] - mean; vs += dd * dd; }
    float rstd = rsqrtf(red8(vs) * (1.f / 128.f) + 1e-5f);
    float cn[16];
#pragma unroll
    for (int i = 0; i < 16; ++i) cn[i] = (cs[i] - mean) * rstd * gs[i];
    u32x4* cw = reinterpret_cast<u32x4*>(&a_cn[rl * 136 + c0]);
    u32x4 w0 = {pk2(cn[0],cn[1]), pk2(cn[2],cn[3]), pk2(cn[4],cn[5]), pk2(cn[6],cn[7])};
    u32x4 w1 = {pk2(cn[8],cn[9]), pk2(cn[10],cn[11]), pk2(cn[12],cn[13]), pk2(cn[14],cn[15])};
    cw[0] = w0; cw[1] = w1;
  }
  __syncthreads();
  const int lane = tid & 63, wave = tid >> 6, lr = lane & 15, lg = lane >> 4;
  f32x4 dS[2][2], dB[2][2];
  gemm32x128(a_cn, WT + 5 * 16384, lr, lg, wave, dS);
  gemm32x128(a_cn, WT + 6 * 16384, lr, lg, wave, dB);
#pragma unroll
  for (int mt = 0; mt < 2; ++mt)
#pragma unroll
    for (int j = 0; j < 2; ++j)
#pragma unroll
      for (int r = 0; r < 4; ++r) {
        int col = (wave * 2 + j) * 16 + lr;
        int rowl = mt * 16 + lg * 4 + r;
        float sc = dS[mt][j][r] + bs[col];
        float xa = sigm(sc) * xnf[rowl * 132 + col] + dB[mt][j][r];
        a_xa[rowl * 136 + col] = f2bf(xa);
      }
  __syncthreads();
  f32x4 dK[2][2], dV[2][2];
  gemm32x128(a_xa, WT + 7 * 16384, lr, lg, wave, dK);
  gemm32x128(a_xa, WT + 8 * 16384, lr, lg, wave, dV);
#pragma unroll
  for (int mt = 0; mt < 2; ++mt)
#pragma unroll
    for (int j = 0; j < 2; ++j)
#pragma unroll
      for (int r = 0; r < 4; ++r) {
        int col = (wave * 2 + j) * 16 + lr;
        int rowl = mt * 16 + lg * 4 + r;
        size_t gr = (size_t)blockIdx.x * 32 + rowl;
        int b = (int)(gr >= SQ);
        int pos = (int)gr - b * SQ;
        int h = col >> 5, dd = col & 31;
        kbf[(((size_t)b * NH + h) * SQ + pos) * DH + dd] = f2bf(dK[mt][j][r]);
        vT[(((size_t)b * NH + h) * DH + dd) * SQ + pos] = f2bf(dV[mt][j][r]);
      }
}

// Flash attention v11: SINGLE-WAVE blocks. 16 q-rows x 768 keys (ksplit=4).
// Pair staged coalesced (2 rows x 512B per f32x4 instruction) into wave-private
// LDS; redistribution to the MFMA C-fragment layout is an in-wave LDS
// round-trip (in-order DS, counted lgkmcnt, NO barriers). Next tile's loads
// issue BEFORE this tile's LDS writes -> compiler emits counted vmcnt (depth-2
// prefetch survives; no vmcnt(0) drain anywhere). Swapped-MFMA algebra (R8,
// verified), defer-max THR=8 (R10, verified), 4-way ksplit merge in finalk.
__global__ __launch_bounds__(64) void attn(
    const u16* __restrict__ qbf, const u16* __restrict__ kbf, const u16* __restrict__ vT,
    const float* __restrict__ pair, const int* __restrict__ mask_q,
    const float* __restrict__ mkf,
    float* __restrict__ part_o, float* __restrict__ part_m, float* __restrict__ part_l) {
  __shared__ float pbuf[16][132];   // pair tile: 16 q-rows x 128 k (f32)
  __shared__ u16 plds[16 * 136];    // P tile: 16 q-rows x 128 k (bf16)
  const int lane = threadIdx.x;
  const int lr = lane & 15, lg = lane >> 4;
  const int bid = blockIdx.x;
  const int bh = bid & 7;                 // XCD spread
  const int rest = bid >> 3;              // 0..767
  const int z = rest & 3, qt = rest >> 2; // z: ksplit, qt: 0..191
  const int b = bh >> 2;
  const int q0 = qt * 16;
  const int k0 = z * 768;
  const bf16x8 aq = ld8(qbf + ((size_t)bh * SQ + q0 + lr) * DH + lg * 8);  // B operand (Q)
  const float mqm1 = 1e9f * ((float)mask_q[b * SQ + q0 + lr] - 1.f);       // per-lane q=lr
  float m = -1e30f, lsum = 0.f;
  const f32x4 zero = {0.f, 0.f, 0.f, 0.f};
  f32x4 o[2]; o[0] = zero; o[1] = zero;
  // staging address: instruction j covers rows 2j+(lane>>5), cols (lane&31)*4
  const int srow = lane >> 5;        // 0/1
  const int scol = (lane & 31) * 4;  // f32 col within tile
  const float* pstage = pair + ((size_t)bh * SQ + q0 + srow) * SQ + scol;
  const float* mrow = mkf + b * SQ;
  const u16* krow = kbf + (size_t)bh * SQ * DH;
  const u16* vrow = vT + (size_t)bh * DH * SQ;

  f32x4 pfA[8], pfB[8];
#pragma unroll
  for (int j = 0; j < 8; ++j)
    pfA[j] = __builtin_nontemporal_load(
        reinterpret_cast<const f32x4*>(pstage + (size_t)(2 * j) * SQ + k0));

#pragma unroll
  for (int t = 0; t < 6; ++t) {
    const int kb = k0 + t * 128;
    f32x4* pf = (t & 1) ? pfB : pfA;   // static after unroll
    f32x4* pfn = (t & 1) ? pfA : pfB;
    // issue next tile's pair loads FIRST -> stage-write below waits only on
    // pf's loads (counted vmcnt), pfn's stay in flight across the whole tile
    if (t < 5) {
#pragma unroll
      for (int j = 0; j < 8; ++j)
        pfn[j] = __builtin_nontemporal_load(
            reinterpret_cast<const f32x4*>(pstage + (size_t)(2 * j) * SQ + kb + 128));
    }
    // stage current tile into LDS (wave-private; in-order DS, no barrier)
#pragma unroll
    for (int j = 0; j < 8; ++j)
      *reinterpret_cast<f32x4*>(&pbuf[2 * j + srow][scol]) = pf[j];
    // K fragments (L2-resident per XCD)
    bf16x8 kf[8];
#pragma unroll
    for (int kt = 0; kt < 8; ++kt)
      kf[kt] = ld8(krow + (size_t)(kb + kt * 16 + lr) * DH + lg * 8);
    // QK^T: C = pair + mask folded (D[row=k], col=q=lr)
    f32x4 s[8];
#pragma unroll
    for (int kt = 0; kt < 8; ++kt) {
      f32x4 pv = *reinterpret_cast<const f32x4*>(&pbuf[lr][kt * 16 + lg * 4]);
      f32x4 mk = *reinterpret_cast<const f32x4*>(mrow + kb + kt * 16 + lg * 4);
      f32x4 c;
      c[0] = fmaf(mqm1, mk[0], pv[0]); c[1] = fmaf(mqm1, mk[1], pv[1]);
      c[2] = fmaf(mqm1, mk[2], pv[2]); c[3] = fmaf(mqm1, mk[3], pv[3]);
      s[kt] = mfma16(kf[kt], aq, c);
    }
    // max over 128 k: in-reg tree + 2 shfl
    f32x4 mx = s[0];
#pragma unroll
    for (int kt = 1; kt < 8; ++kt)
#pragma unroll
      for (int r = 0; r < 4; ++r) mx[r] = fmaxf(mx[r], s[kt][r]);
    float pm = fmaxf(fmaxf(mx[0], mx[1]), fmaxf(mx[2], mx[3]));
    pm = fmaxf(pm, __shfl_xor(pm, 16));
    pm = fmaxf(pm, __shfl_xor(pm, 32));
    // defer-max: rescale only when max grew past threshold
    if (!__all(pm <= m + 8.f)) {
      const float mn = fmaxf(m, pm);
      const float alpha = __expf(m - mn);
      m = mn;
      float al[4];
#pragma unroll
      for (int r = 0; r < 4; ++r)
        al[r] = __builtin_bit_cast(
            float, __builtin_amdgcn_ds_bpermute((lg * 4 + r) << 2,
                                                __builtin_bit_cast(int, alpha)));
#pragma unroll
      for (int hf = 0; hf < 2; ++hf)
#pragma unroll
        for (int r = 0; r < 4; ++r) o[hf][r] *= al[r];
      lsum *= alpha;
    }
    float ps = 0.f;
#pragma unroll
    for (int kt = 0; kt < 8; ++kt)
#pragma unroll
      for (int r = 0; r < 4; ++r) {
        float p = __expf(s[kt][r] - m);
        s[kt][r] = p;
        ps += p;
      }
    lsum += ps;
    // P pack -> wave-private LDS (row q=lr), then PV
#pragma unroll
    for (int kt = 0; kt < 8; ++kt) {
      u32x2 pk = {pk2(s[kt][0], s[kt][1]), pk2(s[kt][2], s[kt][3])};
      *reinterpret_cast<u32x2*>(plds + lr * 136 + kt * 16 + lg * 4) = pk;
    }
#pragma unroll
    for (int kc = 0; kc < 4; ++kc) {
      bf16x8 pa = ld8(plds + lr * 136 + kc * 32 + lg * 8);
#pragma unroll
      for (int hf = 0; hf < 2; ++hf) {
        bf16x8 bv = ld8(vrow + (size_t)(hf * 16 + lr) * SQ + kb + kc * 32 + lg * 8);
        o[hf] = mfma16(pa, bv, o[hf]);
      }
    }
  }
  lsum += __shfl_xor(lsum, 16);
  lsum += __shfl_xor(lsum, 32);
  const int zb = (z * 8 + bh) * SQ;
  if (lane < 16) {
    part_m[zb + q0 + lr] = m;
    part_l[zb + q0 + lr] = lsum;
  }
#pragma unroll
  for (int hf = 0; hf < 2; ++hf)
#pragma unroll
    for (int r = 0; r < 4; ++r)
      part_o[((size_t)(zb + q0 + lg * 4 + r)) * 32 + hf * 16 + lr] = o[hf][r];
}

// finalk: merge 4 k-split partials + gate -> awa (LDS), then (wa @ Wt2) * zc.
__global__ __launch_bounds__(256) void finalk(
    const float* __restrict__ part_o, const float* __restrict__ part_m,
    const float* __restrict__ part_l, const float* __restrict__ gate,
    const u16* __restrict__ WTt2, const float* __restrict__ zc,
    float* __restrict__ out) {
  __shared__ u16 awa[32 * 136];
  const int tid = threadIdx.x, rl = tid >> 3, sub = tid & 7, c0 = sub * 16;
  const int grow = blockIdx.x * 32 + rl;  // [0, 6144)
  const int b = (int)(grow >= SQ), q = grow - b * SQ;
  const int h = sub >> 1, d0 = (sub & 1) * 16;
  const int bh = b * 4 + h;
  int row[4];
  float mz[4];
  float M = -1e30f;
#pragma unroll
  for (int zz = 0; zz < 4; ++zz) {
    row[zz] = (zz * 8 + bh) * SQ + q;
    mz[zz] = part_m[row[zz]];
    M = fmaxf(M, mz[zz]);
  }
  float ez[4];
  float den = 0.f;
#pragma unroll
  for (int zz = 0; zz < 4; ++zz) {
    ez[zz] = __expf(mz[zz] - M);
    den = fmaf(ez[zz], part_l[row[zz]], den);
  }
  const float inv = 1.f / den;
  u32 wb[8];
#pragma unroll
  for (int j4 = 0; j4 < 4; ++j4) {
    f32x4 acc = {0.f, 0.f, 0.f, 0.f};
#pragma unroll
    for (int zz = 0; zz < 4; ++zz) {
      f32x4 oz = *reinterpret_cast<const f32x4*>(part_o + (size_t)row[zz] * 32 + d0 + j4 * 4);
      acc[0] = fmaf(ez[zz], oz[0], acc[0]);
      acc[1] = fmaf(ez[zz], oz[1], acc[1]);
      acc[2] = fmaf(ez[zz], oz[2], acc[2]);
      acc[3] = fmaf(ez[zz], oz[3], acc[3]);
    }
    f32x4 g = *reinterpret_cast<const f32x4*>(gate + (size_t)grow * 128 + c0 + j4 * 4);
    float v0 = acc[0] * inv * g[0];
    float v1 = acc[1] * inv * g[1];
    float v2 = acc[2] * inv * g[2];
    float v3 = acc[3] * inv * g[3];
    wb[j4 * 2 + 0] = pk2(v0, v1);
    wb[j4 * 2 + 1] = pk2(v2, v3);
  }
  u32x4* dstp = reinterpret_cast<u32x4*>(&awa[rl * 136 + c0]);
  u32x4 w0 = {wb[0], wb[1], wb[2], wb[3]};
  u32x4 w1 = {wb[4], wb[5], wb[6], wb[7]};
  dstp[0] = w0; dstp[1] = w1;
  __syncthreads();
  const int lane = tid & 63, wave = tid >> 6, lr = lane & 15, lg = lane >> 4;
  f32x4 d[2][2];
  gemm32x128(awa, WTt2, lr, lg, wave, d);
#pragma unroll
  for (int mt = 0; mt < 2; ++mt)
#pragma unroll
    for (int j = 0; j < 2; ++j)
#pragma unroll
      for (int r = 0; r < 4; ++r) {
        int col = (wave * 2 + j) * 16 + lr;
        size_t gr = (size_t)blockIdx.x * 32 + mt * 16 + lg * 4 + r;
        out[gr * 128 + col] = d[mt][j][r] * zc[gr * 128 + col];
      }
}

extern "C" void kernel_launch(void* const* d_in, const int* in_sizes, int n_in,
                              void* d_out, int out_size, void* d_ws, size_t ws_size,
                              hipStream_t stream) {
  const float* x_q   = (const float*)d_in[0];
  const float* x_k   = (const float*)d_in[1];
  const int* mask_q  = (const int*)d_in[2];
  const int* mask_k  = (const int*)d_in[3];
  const float* pair  = (const float*)d_in[4];
  const float* scq   = (const float*)d_in[5];
  const float* sck   = (const float*)d_in[6];
  const float* gamma_cq = (const float*)d_in[7];
  const float* Wsq   = (const float*)d_in[8];
  const float* bsq   = (const float*)d_in[9];
  const float* Wbq   = (const float*)d_in[10];
  const float* gamma_ck = (const float*)d_in[11];
  const float* Wsk   = (const float*)d_in[12];
  const float* bsk   = (const float*)d_in[13];
  const float* Wbk   = (const float*)d_in[14];
  const float* Wq    = (const float*)d_in[15];
  const float* bq    = (const float*)d_in[16];
  const float* Wk    = (const float*)d_in[17];
  const float* Wv    = (const float*)d_in[18];
  const float* Wg    = (const float*)d_in[19];
  const float* Wt2   = (const float*)d_in[20];
  const float* Wzc   = (const float*)d_in[21];
  const float* bzc   = (const float*)d_in[22];

  char* wsb = (char*)d_ws;
  u16* WT       = (u16*)(wsb);               // 10 x 32KB transposed bf16 weights
  u16* qbf      = (u16*)(wsb + 327680);      // [B,H,S,DH] bf16
  u16* kbf      = (u16*)(wsb + 1900544);     // [B,H,S,DH] bf16
  u16* vT       = (u16*)(wsb + 3473408);     // [B,H,DH,S] bf16
  float* gate   = (float*)(wsb + 5046272);   // [B,S,C] f32
  float* zc     = (float*)(wsb + 8192000);   // [B,S,C] f32
  float* mkf    = (float*)(wsb + 11337728);  // [B,S] f32 mask_k - 1
  float* part_o = (float*)(wsb + 11362304);  // [4,8,SQ,32] f32 (12.6 MB)
  float* part_m = (float*)(wsb + 23945216);  // [4,8,SQ] f32
  float* part_l = (float*)(wsb + 24338432);  // [4,8,SQ] f32
  float* out    = (float*)d_out;

  PrepSrc ps;
  ps.p[0] = Wsq; ps.p[1] = Wbq; ps.p[2] = Wq; ps.p[3] = Wg; ps.p[4] = Wzc;
  ps.p[5] = Wsk; ps.p[6] = Wbk; ps.p[7] = Wk; ps.p[8] = Wv; ps.p[9] = Wt2;

  hipLaunchKernelGGL(prep, dim3(40), dim3(256), 0, stream, ps, WT);
  hipLaunchKernelGGL(rowblock_q, dim3(192), dim3(256), 0, stream,
                     x_q, scq, gamma_cq, bsq, bq, bzc, WT, qbf, gate, zc);
  hipLaunchKernelGGL(rowblock_k, dim3(192), dim3(256), 0, stream,
                     x_k, sck, gamma_ck, bsk, WT, mask_k, kbf, vT, mkf);
  // 6144 single-wave blocks: bh in low 3 bits (XCD spread), then z, then qt
  hipLaunchKernelGGL(attn, dim3(6144), dim3(64), 0, stream,
                     qbf, kbf, vT, pair, mask_q, mkf, part_o, part_m, part_l);
  hipLaunchKernelGGL(finalk, dim3(192), dim3(256), 0, stream,
                     part_o, part_m, part_l, gate, WT + 9 * 16384, zc, out);
}

// Round 12
// 120.152 us; speedup vs baseline: 2.4105x; 1.1760x over previous
//
#include <hip/hip_runtime.h>
#include <hip/hip_bf16.h>

typedef unsigned short u16;
typedef unsigned int u32;
typedef __attribute__((ext_vector_type(4))) float f32x4;
typedef __attribute__((ext_vector_type(4))) u32 u32x4;
typedef __attribute__((ext_vector_type(8))) __bf16 bf16x8;

#define SQ 3072
#define NH 4
#define DH 32

static __device__ __forceinline__ u16 f2bf(float f) {
  return __builtin_bit_cast(u16, (__bf16)f);
}
static __device__ __forceinline__ u32 pk2(float a, float b) {
  return (u32)f2bf(a) | ((u32)f2bf(b) << 16);
}
static __device__ __forceinline__ bf16x8 ld8(const u16* p) {
  return __builtin_bit_cast(bf16x8, *reinterpret_cast<const u32x4*>(p));
}
static __device__ __forceinline__ f32x4 mfma16(bf16x8 a, bf16x8 b, f32x4 c) {
  return __builtin_amdgcn_mfma_f32_16x16x32_bf16(a, b, c, 0, 0, 0);
}
static __device__ __forceinline__ float sigm(float x) { return 1.0f / (1.0f + __expf(-x)); }
static __device__ __forceinline__ float red16(float v) {
  v += __shfl_xor(v, 1); v += __shfl_xor(v, 2);
  v += __shfl_xor(v, 4); v += __shfl_xor(v, 8);
  return v;
}

// 8-wave GEMM: A 32x128 bf16 in LDS (stride 136), B = WT[cout][k] (128x128).
// Wave w owns col-tile w*16..w*16+15; d[mt] = rows mt*16+lg*4+r, col w*16+lr.
static __device__ __forceinline__ void gemm8(
    const u16* a, const u16* wt, int lr, int lg, int w, f32x4 d[2]) {
  f32x4 z = {0.f, 0.f, 0.f, 0.f};
  d[0] = z; d[1] = z;
#pragma unroll
  for (int kc = 0; kc < 4; ++kc) {
    int ko = kc * 32 + lg * 8;
    bf16x8 a0 = ld8(a + lr * 136 + ko);
    bf16x8 a1 = ld8(a + (16 + lr) * 136 + ko);
    bf16x8 b0 = ld8(wt + (w * 16 + lr) * 128 + ko);
    d[0] = mfma16(a0, b0, d[0]);
    d[1] = mfma16(a1, b0, d[1]);
  }
}

struct PrepSrc { const float* p[10]; };

// Coalesced transpose: dst[m][cout][k] = W_m[k][cout], via LDS tile.
__global__ __launch_bounds__(256) void prep(PrepSrc s, u16* __restrict__ dst) {
  __shared__ float tl[32][132];
  const int mm = blockIdx.x >> 2, c = blockIdx.x & 3;
  const int tid = threadIdx.x;
  {
    const int krl = tid >> 3, col0 = (tid & 7) * 16;
    const int kr = c * 32 + krl;
    const float* src = s.p[mm] + kr * 128 + col0;
#pragma unroll
    for (int j = 0; j < 4; ++j) {
      f32x4 v = *reinterpret_cast<const f32x4*>(src + j * 4);
      tl[krl][col0 + j * 4 + 0] = v[0];
      tl[krl][col0 + j * 4 + 1] = v[1];
      tl[krl][col0 + j * 4 + 2] = v[2];
      tl[krl][col0 + j * 4 + 3] = v[3];
    }
  }
  __syncthreads();
  const int co = tid >> 1, kc0 = (tid & 1) * 16;
  u32 wbuf[8];
#pragma unroll
  for (int j = 0; j < 8; ++j)
    wbuf[j] = pk2(tl[kc0 + 2 * j][co], tl[kc0 + 2 * j + 1][co]);
  u32x4* dp = reinterpret_cast<u32x4*>(dst + mm * 16384 + co * 128 + c * 32 + kc0);
  u32x4 w0 = {wbuf[0], wbuf[1], wbuf[2], wbuf[3]};
  u32x4 w1 = {wbuf[4], wbuf[5], wbuf[6], wbuf[7]};
  dp[0] = w0; dp[1] = w1;
}

// Fused q-side + k-side row blocks. Grid 384: [0,192) q-side, [192,384) k-side.
// 512 threads / 8 waves: LN over 16 threads/row, GEMM col-space split 8 ways
// (halves per-phase serial latency vs the 4-wave version).
__global__ __launch_bounds__(512) void rowblocks(
    const float* __restrict__ x_q, const float* __restrict__ scq,
    const float* __restrict__ gamma_cq, const float* __restrict__ bsq,
    const float* __restrict__ bq, const float* __restrict__ bzc,
    const float* __restrict__ x_k, const float* __restrict__ sck,
    const float* __restrict__ gamma_ck, const float* __restrict__ bsk,
    const u16* __restrict__ WT,
    u16* __restrict__ qbf, float* __restrict__ gate, float* __restrict__ zc,
    u16* __restrict__ kbf, u16* __restrict__ vT) {
  __shared__ float xnf[32 * 132];
  __shared__ u16 a_cn[32 * 136];
  __shared__ u16 a_raw[32 * 136];
  __shared__ u16 a_xa[32 * 136];
  const int tid = threadIdx.x;
  const bool qside = blockIdx.x < 192;
  const int blk = qside ? blockIdx.x : blockIdx.x - 192;
  const float* x     = qside ? x_q : x_k;
  const float* cond  = qside ? scq : sck;
  const float* gamma = qside ? gamma_cq : gamma_ck;
  const float* bs    = qside ? bsq : bsk;
  const int rl = tid >> 4, sub = tid & 15, c0 = sub * 8;
  const size_t grow = (size_t)blk * 32 + rl;

  {  // LN(x) -> xnf (f32)
    float xs[8];
    const float4* xr = reinterpret_cast<const float4*>(x + grow * 128 + c0);
    float4 t0 = xr[0], t1 = xr[1];
    xs[0]=t0.x; xs[1]=t0.y; xs[2]=t0.z; xs[3]=t0.w;
    xs[4]=t1.x; xs[5]=t1.y; xs[6]=t1.z; xs[7]=t1.w;
    float s = 0.f;
#pragma unroll
    for (int i = 0; i < 8; ++i) s += xs[i];
    float mean = red16(s) * (1.f / 128.f);
    float vs = 0.f;
#pragma unroll
    for (int i = 0; i < 8; ++i) { float dd = xs[i] - mean; vs += dd * dd; }
    float rstd = rsqrtf(red16(vs) * (1.f / 128.f) + 1e-5f);
    float4* xw = reinterpret_cast<float4*>(&xnf[rl * 132 + c0]);
    float4 o0, o1;
    o0.x=(xs[0]-mean)*rstd; o0.y=(xs[1]-mean)*rstd; o0.z=(xs[2]-mean)*rstd; o0.w=(xs[3]-mean)*rstd;
    o1.x=(xs[4]-mean)*rstd; o1.y=(xs[5]-mean)*rstd; o1.z=(xs[6]-mean)*rstd; o1.w=(xs[7]-mean)*rstd;
    xw[0] = o0; xw[1] = o1;
  }
  {  // LN(cond)*gamma -> a_cn (bf16); q-side also raw cond -> a_raw
    float cs[8], gs[8];
    const float4* cr = reinterpret_cast<const float4*>(cond + grow * 128 + c0);
    const float4* gr = reinterpret_cast<const float4*>(gamma + c0);
    float4 c_0 = cr[0], c_1 = cr[1], g_0 = gr[0], g_1 = gr[1];
    cs[0]=c_0.x; cs[1]=c_0.y; cs[2]=c_0.z; cs[3]=c_0.w;
    cs[4]=c_1.x; cs[5]=c_1.y; cs[6]=c_1.z; cs[7]=c_1.w;
    gs[0]=g_0.x; gs[1]=g_0.y; gs[2]=g_0.z; gs[3]=g_0.w;
    gs[4]=g_1.x; gs[5]=g_1.y; gs[6]=g_1.z; gs[7]=g_1.w;
    float s = 0.f;
#pragma unroll
    for (int i = 0; i < 8; ++i) s += cs[i];
    float mean = red16(s) * (1.f / 128.f);
    float vs = 0.f;
#pragma unroll
    for (int i = 0; i < 8; ++i) { float dd = cs[i] - mean; vs += dd * dd; }
    float rstd = rsqrtf(red16(vs) * (1.f / 128.f) + 1e-5f);
    float cn[8];
#pragma unroll
    for (int i = 0; i < 8; ++i) cn[i] = (cs[i] - mean) * rstd * gs[i];
    u32x4 cw = {pk2(cn[0],cn[1]), pk2(cn[2],cn[3]), pk2(cn[4],cn[5]), pk2(cn[6],cn[7])};
    *reinterpret_cast<u32x4*>(&a_cn[rl * 136 + c0]) = cw;
    if (qside) {
      u32x4 rw = {pk2(cs[0],cs[1]), pk2(cs[2],cs[3]), pk2(cs[4],cs[5]), pk2(cs[6],cs[7])};
      *reinterpret_cast<u32x4*>(&a_raw[rl * 136 + c0]) = rw;
    }
  }
  __syncthreads();
  const int lane = tid & 63, w = tid >> 6, lr = lane & 15, lg = lane >> 4;
  const int wtbase = qside ? 0 : 5;
  f32x4 dS[2], dB[2];
  gemm8(a_cn, WT + (wtbase + 0) * 16384, lr, lg, w, dS);
  gemm8(a_cn, WT + (wtbase + 1) * 16384, lr, lg, w, dB);
  const int col = w * 16 + lr;
#pragma unroll
  for (int mt = 0; mt < 2; ++mt)
#pragma unroll
    for (int r = 0; r < 4; ++r) {
      int rowl = mt * 16 + lg * 4 + r;
      float sc = dS[mt][r] + bs[col];
      float xa = sigm(sc) * xnf[rowl * 132 + col] + dB[mt][r];
      a_xa[rowl * 136 + col] = f2bf(xa);
    }
  __syncthreads();
  if (qside) {
    f32x4 dQ[2], dG[2], dZ[2];
    gemm8(a_xa,  WT + 2 * 16384, lr, lg, w, dQ);
    gemm8(a_xa,  WT + 3 * 16384, lr, lg, w, dG);
    gemm8(a_raw, WT + 4 * 16384, lr, lg, w, dZ);
#pragma unroll
    for (int mt = 0; mt < 2; ++mt)
#pragma unroll
      for (int r = 0; r < 4; ++r) {
        int rowl = mt * 16 + lg * 4 + r;
        size_t gr = (size_t)blk * 32 + rowl;
        int b = (int)(gr >= SQ);
        int pos = (int)gr - b * SQ;
        float qv = (dQ[mt][r] + bq[col]) * 0.17677669529663687f;  // Dh^-0.5
        qbf[(((size_t)b * NH + (col >> 5)) * SQ + pos) * DH + (col & 31)] = f2bf(qv);
        gate[gr * 128 + col] = sigm(dG[mt][r]);
        zc[gr * 128 + col] = sigm(dZ[mt][r] + bzc[col]);
      }
  } else {
    f32x4 dK[2], dV[2];
    gemm8(a_xa, WT + 7 * 16384, lr, lg, w, dK);
    gemm8(a_xa, WT + 8 * 16384, lr, lg, w, dV);
    const int h = col >> 5, dd = col & 31;
#pragma unroll
    for (int mt = 0; mt < 2; ++mt)
#pragma unroll
      for (int r = 0; r < 4; ++r) {
        int rowl = mt * 16 + lg * 4 + r;
        size_t gr = (size_t)blk * 32 + rowl;
        int b = (int)(gr >= SQ);
        int pos = (int)gr - b * SQ;
        kbf[(((size_t)b * NH + h) * SQ + pos) * DH + dd] = f2bf(dK[mt][r]);
        vT[(((size_t)b * NH + h) * DH + dd) * SQ + pos] = f2bf(dV[mt][r]);
      }
  }
}

// Flash attention — EXACT round-5 best (measured 88us): block-cooperative pair
// staging, 4 waves, 12 tiles of 256 keys, in-block 4-way k merge, gated wa out.
__global__ __launch_bounds__(256) void attn(
    const u16* __restrict__ qbf, const u16* __restrict__ kbf, const u16* __restrict__ vT,
    const float* __restrict__ pair, const int* __restrict__ mask_q,
    const int* __restrict__ mask_k, const float* __restrict__ gate,
    u16* __restrict__ wa) {
  __shared__ float pbuf[2][16][260];   // pair tile dbuf (stride 260: 2-way banks)
  __shared__ u16 plds[4][16 * 72];     // per-wave P tile
  __shared__ float mb[4][16][34];      // merge: o[0..31], m[32], l[33]
  const int tid = threadIdx.x, lane = tid & 63, w = tid >> 6, lr = lane & 15, lg = lane >> 4;
  const int bid = blockIdx.x;
  const int bh = bid & 7, qt = bid >> 3;  // bh in low bits -> XCD pinning
  const int b = bh >> 2, h = bh & 3;
  const int q0 = qt * 16;
  const bf16x8 aq = ld8(qbf + ((size_t)bh * SQ + q0 + lr) * DH + lg * 8);
  float mqm1[4];
#pragma unroll
  for (int r = 0; r < 4; ++r)
    mqm1[r] = 1e9f * ((float)mask_q[b * SQ + q0 + lg * 4 + r] - 1.f);
  float m[4], l[4];
#pragma unroll
  for (int r = 0; r < 4; ++r) { m[r] = -1e30f; l[r] = 0.f; }
  const f32x4 zero = {0.f, 0.f, 0.f, 0.f};
  f32x4 o[2]; o[0] = zero; o[1] = zero;
  const float* prow0 = pair + ((size_t)bh * SQ + q0 + w * 4) * SQ;
  u16* pw = plds[w];
  f32x4 pf[4];
#pragma unroll
  for (int j = 0; j < 4; ++j)
    pf[j] = __builtin_nontemporal_load(
        reinterpret_cast<const f32x4*>(prow0 + (size_t)j * SQ + lane * 4));
  for (int t = 0; t < 12; ++t) {
    const int bsel = t & 1;
#pragma unroll
    for (int j = 0; j < 4; ++j)
      *reinterpret_cast<f32x4*>(&pbuf[bsel][w * 4 + j][lane * 4]) = pf[j];
    __syncthreads();  // tile t visible to all waves (drains vmcnt)
    if (t < 11) {
#pragma unroll
      for (int j = 0; j < 4; ++j)
        pf[j] = __builtin_nontemporal_load(
            reinterpret_cast<const f32x4*>(prow0 + (size_t)j * SQ + (t + 1) * 256 + lane * 4));
    }
    const int kb = t * 256 + w * 64;  // this wave's 64-key chunk
    f32x4 s[4];
#pragma unroll
    for (int kt = 0; kt < 4; ++kt)
      s[kt] = mfma16(aq, ld8(kbf + ((size_t)bh * SQ + kb + kt * 16 + lr) * DH + lg * 8), zero);
    float mk1[4];
#pragma unroll
    for (int kt = 0; kt < 4; ++kt)
      mk1[kt] = (float)mask_k[b * SQ + kb + kt * 16 + lr] - 1.f;
#pragma unroll
    for (int kt = 0; kt < 4; ++kt)
#pragma unroll
      for (int r = 0; r < 4; ++r) {
        float pv = pbuf[bsel][lg * 4 + r][w * 64 + kt * 16 + lr];
        s[kt][r] += fmaf(mqm1[r], mk1[kt], pv);  // exact-1e9 masking preserved
      }
    float alpha[4];
#pragma unroll
    for (int r = 0; r < 4; ++r) {
      float mx = fmaxf(fmaxf(s[0][r], s[1][r]), fmaxf(s[2][r], s[3][r]));
      mx = fmaxf(mx, __shfl_xor(mx, 1));
      mx = fmaxf(mx, __shfl_xor(mx, 2));
      mx = fmaxf(mx, __shfl_xor(mx, 4));
      mx = fmaxf(mx, __shfl_xor(mx, 8));
      float mn = fmaxf(m[r], mx);
      alpha[r] = __expf(m[r] - mn);
      m[r] = mn;
    }
#pragma unroll
    for (int r = 0; r < 4; ++r) {
      float acc = 0.f;
#pragma unroll
      for (int kt = 0; kt < 4; ++kt) {
        float p = __expf(s[kt][r] - m[r]);
        s[kt][r] = p;
        acc += p;
      }
      acc += __shfl_xor(acc, 1); acc += __shfl_xor(acc, 2);
      acc += __shfl_xor(acc, 4); acc += __shfl_xor(acc, 8);
      l[r] = l[r] * alpha[r] + acc;
      o[0][r] *= alpha[r];
      o[1][r] *= alpha[r];
    }
#pragma unroll
    for (int kt = 0; kt < 4; ++kt)
#pragma unroll
      for (int r = 0; r < 4; ++r)
        pw[(lg * 4 + r) * 72 + kt * 16 + lr] = f2bf(s[kt][r]);
#pragma unroll
    for (int kc = 0; kc < 2; ++kc) {
      bf16x8 pa = ld8(pw + lr * 72 + kc * 32 + lg * 8);
#pragma unroll
      for (int hf = 0; hf < 2; ++hf) {
        bf16x8 bv = ld8(vT + ((size_t)bh * DH + hf * 16 + lr) * SQ + kb + kc * 32 + lg * 8);
        o[hf] = mfma16(pa, bv, o[hf]);
      }
    }
  }
  // block merge of 4 wave-partials (k-split within block)
#pragma unroll
  for (int r = 0; r < 4; ++r) {
    int row = lg * 4 + r;
    mb[w][row][lr] = o[0][r];
    mb[w][row][16 + lr] = o[1][r];
    if (lr == 0) { mb[w][row][32] = m[r]; mb[w][row][33] = l[r]; }
  }
  __syncthreads();
#pragma unroll
  for (int it = 0; it < 2; ++it) {
    int q = (tid >> 5) + it * 8;  // 0..15
    int d = tid & 31;
    float m0 = mb[0][q][32], m1 = mb[1][q][32], m2 = mb[2][q][32], m3 = mb[3][q][32];
    float mm = fmaxf(fmaxf(m0, m1), fmaxf(m2, m3));
    float ll = 0.f, oo = 0.f;
#pragma unroll
    for (int w4 = 0; w4 < 4; ++w4) {
      float e = __expf(mb[w4][q][32] - mm);
      ll = fmaf(e, mb[w4][q][33], ll);
      oo = fmaf(e, mb[w4][q][d], oo);
    }
    size_t gi = ((size_t)b * SQ + q0 + q) * 128 + h * 32 + d;
    wa[gi] = f2bf((oo / ll) * gate[gi]);
  }
}

// out = (wa @ Wt2) * zc — 512 threads / 8-wave GEMM split.
__global__ __launch_bounds__(512) void finalk(
    const u16* __restrict__ wa, const u16* __restrict__ WTt2,
    const float* __restrict__ zc, float* __restrict__ out) {
  __shared__ u16 awa[32 * 136];
  const int tid = threadIdx.x, rl = tid >> 4, sub = tid & 15, c0 = sub * 8;
  const size_t grow = (size_t)blockIdx.x * 32 + rl;
  *reinterpret_cast<u32x4*>(&awa[rl * 136 + c0]) =
      *reinterpret_cast<const u32x4*>(wa + grow * 128 + c0);
  __syncthreads();
  const int lane = tid & 63, w = tid >> 6, lr = lane & 15, lg = lane >> 4;
  f32x4 d[2];
  gemm8(awa, WTt2, lr, lg, w, d);
  const int col = w * 16 + lr;
#pragma unroll
  for (int mt = 0; mt < 2; ++mt)
#pragma unroll
    for (int r = 0; r < 4; ++r) {
      size_t gr = (size_t)blockIdx.x * 32 + mt * 16 + lg * 4 + r;
      out[gr * 128 + col] = d[mt][r] * zc[gr * 128 + col];
    }
}

extern "C" void kernel_launch(void* const* d_in, const int* in_sizes, int n_in,
                              void* d_out, int out_size, void* d_ws, size_t ws_size,
                              hipStream_t stream) {
  const float* x_q   = (const float*)d_in[0];
  const float* x_k   = (const float*)d_in[1];
  const int* mask_q  = (const int*)d_in[2];
  const int* mask_k  = (const int*)d_in[3];
  const float* pair  = (const float*)d_in[4];
  const float* scq   = (const float*)d_in[5];
  const float* sck   = (const float*)d_in[6];
  const float* gamma_cq = (const float*)d_in[7];
  const float* Wsq   = (const float*)d_in[8];
  const float* bsq   = (const float*)d_in[9];
  const float* Wbq   = (const float*)d_in[10];
  const float* gamma_ck = (const float*)d_in[11];
  const float* Wsk   = (const float*)d_in[12];
  const float* bsk   = (const float*)d_in[13];
  const float* Wbk   = (const float*)d_in[14];
  const float* Wq    = (const float*)d_in[15];
  const float* bq    = (const float*)d_in[16];
  const float* Wk    = (const float*)d_in[17];
  const float* Wv    = (const float*)d_in[18];
  const float* Wg    = (const float*)d_in[19];
  const float* Wt2   = (const float*)d_in[20];
  const float* Wzc   = (const float*)d_in[21];
  const float* bzc   = (const float*)d_in[22];

  char* wsb = (char*)d_ws;
  u16* WT     = (u16*)(wsb);                 // 10 x 32KB transposed bf16 weights
  u16* qbf    = (u16*)(wsb + 327680);        // [B,H,S,DH] bf16
  u16* kbf    = (u16*)(wsb + 1900544);       // [B,H,S,DH] bf16
  u16* vT     = (u16*)(wsb + 3473408);       // [B,H,DH,S] bf16
  float* gate = (float*)(wsb + 5046272);     // [B,S,C] f32
  float* zc   = (float*)(wsb + 8192000);     // [B,S,C] f32
  u16* wa     = (u16*)(wsb + 11337728);      // [B,S,C] bf16
  float* out  = (float*)d_out;

  PrepSrc ps;
  ps.p[0] = Wsq; ps.p[1] = Wbq; ps.p[2] = Wq; ps.p[3] = Wg; ps.p[4] = Wzc;
  ps.p[5] = Wsk; ps.p[6] = Wbk; ps.p[7] = Wk; ps.p[8] = Wv; ps.p[9] = Wt2;

  hipLaunchKernelGGL(prep, dim3(40), dim3(256), 0, stream, ps, WT);
  // fused q-side + k-side (one launch, concurrent execution)
  hipLaunchKernelGGL(rowblocks, dim3(384), dim3(512), 0, stream,
                     x_q, scq, gamma_cq, bsq, bq, bzc,
                     x_k, sck, gamma_ck, bsk, WT, qbf, gate, zc, kbf, vT);
  hipLaunchKernelGGL(attn, dim3(8 * 192), dim3(256), 0, stream,
                     qbf, kbf, vT, pair, mask_q, mask_k, gate, wa);
  hipLaunchKernelGGL(finalk, dim3(192), dim3(512), 0, stream, wa, WT + 9 * 16384, zc, out);
}

// Round 13
// 117.272 us; speedup vs baseline: 2.4697x; 1.0246x over previous
//
#include <hip/hip_runtime.h>
#include <hip/hip_bf16.h>

typedef unsigned short u16;
typedef unsigned int u32;
typedef __attribute__((ext_vector_type(4))) float f32x4;
typedef __attribute__((ext_vector_type(4))) u32 u32x4;
typedef __attribute__((ext_vector_type(2))) u32 u32x2;
typedef __attribute__((ext_vector_type(8))) __bf16 bf16x8;

#define SQ 3072
#define NH 4
#define DH 32

static __device__ __forceinline__ u16 f2bf(float f) {
  return __builtin_bit_cast(u16, (__bf16)f);
}
static __device__ __forceinline__ u32 pk2(float a, float b) {
  return (u32)f2bf(a) | ((u32)f2bf(b) << 16);
}
static __device__ __forceinline__ bf16x8 ld8(const u16* p) {
  return __builtin_bit_cast(bf16x8, *reinterpret_cast<const u32x4*>(p));
}
static __device__ __forceinline__ f32x4 mfma16(bf16x8 a, bf16x8 b, f32x4 c) {
  return __builtin_amdgcn_mfma_f32_16x16x32_bf16(a, b, c, 0, 0, 0);
}
static __device__ __forceinline__ float sigm(float x) { return 1.0f / (1.0f + __expf(-x)); }
static __device__ __forceinline__ float red16(float v) {
  v += __shfl_xor(v, 1); v += __shfl_xor(v, 2);
  v += __shfl_xor(v, 4); v += __shfl_xor(v, 8);
  return v;
}

// 8-wave GEMM: A 32x128 bf16 in LDS (stride 136), B = WT[cout][k] (128x128).
static __device__ __forceinline__ void gemm8(
    const u16* a, const u16* wt, int lr, int lg, int w, f32x4 d[2]) {
  f32x4 z = {0.f, 0.f, 0.f, 0.f};
  d[0] = z; d[1] = z;
#pragma unroll
  for (int kc = 0; kc < 4; ++kc) {
    int ko = kc * 32 + lg * 8;
    bf16x8 a0 = ld8(a + lr * 136 + ko);
    bf16x8 a1 = ld8(a + (16 + lr) * 136 + ko);
    bf16x8 b0 = ld8(wt + (w * 16 + lr) * 128 + ko);
    d[0] = mfma16(a0, b0, d[0]);
    d[1] = mfma16(a1, b0, d[1]);
  }
}

struct PrepSrc { const float* p[10]; };

// Coalesced transpose: dst[m][cout][k] = W_m[k][cout], via LDS tile.
__global__ __launch_bounds__(256) void prep(PrepSrc s, u16* __restrict__ dst) {
  __shared__ float tl[32][132];
  const int mm = blockIdx.x >> 2, c = blockIdx.x & 3;
  const int tid = threadIdx.x;
  {
    const int krl = tid >> 3, col0 = (tid & 7) * 16;
    const int kr = c * 32 + krl;
    const float* src = s.p[mm] + kr * 128 + col0;
#pragma unroll
    for (int j = 0; j < 4; ++j) {
      f32x4 v = *reinterpret_cast<const f32x4*>(src + j * 4);
      tl[krl][col0 + j * 4 + 0] = v[0];
      tl[krl][col0 + j * 4 + 1] = v[1];
      tl[krl][col0 + j * 4 + 2] = v[2];
      tl[krl][col0 + j * 4 + 3] = v[3];
    }
  }
  __syncthreads();
  const int co = tid >> 1, kc0 = (tid & 1) * 16;
  u32 wbuf[8];
#pragma unroll
  for (int j = 0; j < 8; ++j)
    wbuf[j] = pk2(tl[kc0 + 2 * j][co], tl[kc0 + 2 * j + 1][co]);
  u32x4* dp = reinterpret_cast<u32x4*>(dst + mm * 16384 + co * 128 + c * 32 + kc0);
  u32x4 w0 = {wbuf[0], wbuf[1], wbuf[2], wbuf[3]};
  u32x4 w1 = {wbuf[4], wbuf[5], wbuf[6], wbuf[7]};
  dp[0] = w0; dp[1] = w1;
}

// Fused q-side + k-side row blocks (512 threads / 8 waves). k-side also emits
// mkf = (mask_k - 1) as f32 for attn's C-fold.
__global__ __launch_bounds__(512) void rowblocks(
    const float* __restrict__ x_q, const float* __restrict__ scq,
    const float* __restrict__ gamma_cq, const float* __restrict__ bsq,
    const float* __restrict__ bq, const float* __restrict__ bzc,
    const float* __restrict__ x_k, const float* __restrict__ sck,
    const float* __restrict__ gamma_ck, const float* __restrict__ bsk,
    const u16* __restrict__ WT, const int* __restrict__ mask_k,
    u16* __restrict__ qbf, float* __restrict__ gate, float* __restrict__ zc,
    u16* __restrict__ kbf, u16* __restrict__ vT, float* __restrict__ mkf) {
  __shared__ float xnf[32 * 132];
  __shared__ u16 a_cn[32 * 136];
  __shared__ u16 a_raw[32 * 136];
  __shared__ u16 a_xa[32 * 136];
  const int tid = threadIdx.x;
  const bool qside = blockIdx.x < 192;
  const int blk = qside ? blockIdx.x : blockIdx.x - 192;
  const float* x     = qside ? x_q : x_k;
  const float* cond  = qside ? scq : sck;
  const float* gamma = qside ? gamma_cq : gamma_ck;
  const float* bs    = qside ? bsq : bsk;
  const int rl = tid >> 4, sub = tid & 15, c0 = sub * 8;
  const size_t grow = (size_t)blk * 32 + rl;
  if (!qside && tid < 32) {
    size_t g2 = (size_t)blk * 32 + tid;
    mkf[g2] = (float)mask_k[g2] - 1.f;
  }

  {  // LN(x) -> xnf (f32)
    float xs[8];
    const float4* xr = reinterpret_cast<const float4*>(x + grow * 128 + c0);
    float4 t0 = xr[0], t1 = xr[1];
    xs[0]=t0.x; xs[1]=t0.y; xs[2]=t0.z; xs[3]=t0.w;
    xs[4]=t1.x; xs[5]=t1.y; xs[6]=t1.z; xs[7]=t1.w;
    float s = 0.f;
#pragma unroll
    for (int i = 0; i < 8; ++i) s += xs[i];
    float mean = red16(s) * (1.f / 128.f);
    float vs = 0.f;
#pragma unroll
    for (int i = 0; i < 8; ++i) { float dd = xs[i] - mean; vs += dd * dd; }
    float rstd = rsqrtf(red16(vs) * (1.f / 128.f) + 1e-5f);
    float4* xw = reinterpret_cast<float4*>(&xnf[rl * 132 + c0]);
    float4 o0, o1;
    o0.x=(xs[0]-mean)*rstd; o0.y=(xs[1]-mean)*rstd; o0.z=(xs[2]-mean)*rstd; o0.w=(xs[3]-mean)*rstd;
    o1.x=(xs[4]-mean)*rstd; o1.y=(xs[5]-mean)*rstd; o1.z=(xs[6]-mean)*rstd; o1.w=(xs[7]-mean)*rstd;
    xw[0] = o0; xw[1] = o1;
  }
  {  // LN(cond)*gamma -> a_cn; q-side raw cond -> a_raw
    float cs[8], gs[8];
    const float4* cr = reinterpret_cast<const float4*>(cond + grow * 128 + c0);
    const float4* gr = reinterpret_cast<const float4*>(gamma + c0);
    float4 c_0 = cr[0], c_1 = cr[1], g_0 = gr[0], g_1 = gr[1];
    cs[0]=c_0.x; cs[1]=c_0.y; cs[2]=c_0.z; cs[3]=c_0.w;
    cs[4]=c_1.x; cs[5]=c_1.y; cs[6]=c_1.z; cs[7]=c_1.w;
    gs[0]=g_0.x; gs[1]=g_0.y; gs[2]=g_0.z; gs[3]=g_0.w;
    gs[4]=g_1.x; gs[5]=g_1.y; gs[6]=g_1.z; gs[7]=g_1.w;
    float s = 0.f;
#pragma unroll
    for (int i = 0; i < 8; ++i) s += cs[i];
    float mean = red16(s) * (1.f / 128.f);
    float vs = 0.f;
#pragma unroll
    for (int i = 0; i < 8; ++i) { float dd = cs[i] - mean; vs += dd * dd; }
    float rstd = rsqrtf(red16(vs) * (1.f / 128.f) + 1e-5f);
    float cn[8];
#pragma unroll
    for (int i = 0; i < 8; ++i) cn[i] = (cs[i] - mean) * rstd * gs[i];
    u32x4 cw = {pk2(cn[0],cn[1]), pk2(cn[2],cn[3]), pk2(cn[4],cn[5]), pk2(cn[6],cn[7])};
    *reinterpret_cast<u32x4*>(&a_cn[rl * 136 + c0]) = cw;
    if (qside) {
      u32x4 rw = {pk2(cs[0],cs[1]), pk2(cs[2],cs[3]), pk2(cs[4],cs[5]), pk2(cs[6],cs[7])};
      *reinterpret_cast<u32x4*>(&a_raw[rl * 136 + c0]) = rw;
    }
  }
  __syncthreads();
  const int lane = tid & 63, w = tid >> 6, lr = lane & 15, lg = lane >> 4;
  const int wtbase = qside ? 0 : 5;
  f32x4 dS[2], dB[2];
  gemm8(a_cn, WT + (wtbase + 0) * 16384, lr, lg, w, dS);
  gemm8(a_cn, WT + (wtbase + 1) * 16384, lr, lg, w, dB);
  const int col = w * 16 + lr;
#pragma unroll
  for (int mt = 0; mt < 2; ++mt)
#pragma unroll
    for (int r = 0; r < 4; ++r) {
      int rowl = mt * 16 + lg * 4 + r;
      float sc = dS[mt][r] + bs[col];
      float xa = sigm(sc) * xnf[rowl * 132 + col] + dB[mt][r];
      a_xa[rowl * 136 + col] = f2bf(xa);
    }
  __syncthreads();
  if (qside) {
    f32x4 dQ[2], dG[2], dZ[2];
    gemm8(a_xa,  WT + 2 * 16384, lr, lg, w, dQ);
    gemm8(a_xa,  WT + 3 * 16384, lr, lg, w, dG);
    gemm8(a_raw, WT + 4 * 16384, lr, lg, w, dZ);
#pragma unroll
    for (int mt = 0; mt < 2; ++mt)
#pragma unroll
      for (int r = 0; r < 4; ++r) {
        int rowl = mt * 16 + lg * 4 + r;
        size_t gr = (size_t)blk * 32 + rowl;
        int b = (int)(gr >= SQ);
        int pos = (int)gr - b * SQ;
        float qv = (dQ[mt][r] + bq[col]) * 0.17677669529663687f;  // Dh^-0.5
        qbf[(((size_t)b * NH + (col >> 5)) * SQ + pos) * DH + (col & 31)] = f2bf(qv);
        gate[gr * 128 + col] = sigm(dG[mt][r]);
        zc[gr * 128 + col] = sigm(dZ[mt][r] + bzc[col]);
      }
  } else {
    f32x4 dK[2], dV[2];
    gemm8(a_xa, WT + 7 * 16384, lr, lg, w, dK);
    gemm8(a_xa, WT + 8 * 16384, lr, lg, w, dV);
    const int h = col >> 5, dd = col & 31;
#pragma unroll
    for (int mt = 0; mt < 2; ++mt)
#pragma unroll
      for (int r = 0; r < 4; ++r) {
        int rowl = mt * 16 + lg * 4 + r;
        size_t gr = (size_t)blk * 32 + rowl;
        int b = (int)(gr >= SQ);
        int pos = (int)gr - b * SQ;
        kbf[(((size_t)b * NH + h) * SQ + pos) * DH + dd] = f2bf(dK[mt][r]);
        vT[(((size_t)b * NH + h) * DH + dd) * SQ + pos] = f2bf(dV[mt][r]);
      }
  }
}

// Flash attention v13: R5's cooperative-staging skeleton (coalesced pair loads,
// barriers, 12x256 tiles, in-block merge) + R8's swapped-operand compute core
// (pair+mask folded into MFMA C; max in-register; l per-lane partial) + R10's
// defer-max. Memory pattern identical to the measured-88us R5 kernel; per-tile
// VALU ~200->~60, dependent shfl chains 32->2.
__global__ __launch_bounds__(256) void attn(
    const u16* __restrict__ qbf, const u16* __restrict__ kbf, const u16* __restrict__ vT,
    const float* __restrict__ pair, const int* __restrict__ mask_q,
    const float* __restrict__ mkf, const float* __restrict__ gate,
    u16* __restrict__ wa) {
  __shared__ float pbuf[2][16][260];   // pair tile dbuf
  __shared__ u16 plds[4][16 * 72];     // per-wave P tile (row q, stride 72)
  __shared__ float mb[4][16][34];      // merge: o[0..31], m[32], l[33]
  const int tid = threadIdx.x, lane = tid & 63, w = tid >> 6, lr = lane & 15, lg = lane >> 4;
  const int bid = blockIdx.x;
  const int bh = bid & 7, qt = bid >> 3;  // bh in low bits -> XCD pinning
  const int b = bh >> 2, h = bh & 3;
  const int q0 = qt * 16;
  const bf16x8 aq = ld8(qbf + ((size_t)bh * SQ + q0 + lr) * DH + lg * 8);  // B op (col q=lr)
  const float mqm1 = 1e9f * ((float)mask_q[b * SQ + q0 + lr] - 1.f);       // per-lane q=lr
  float m = -1e30f, lsum = 0.f;
  const f32x4 zero = {0.f, 0.f, 0.f, 0.f};
  f32x4 o[2]; o[0] = zero; o[1] = zero;
  const float* prow0 = pair + ((size_t)bh * SQ + q0 + w * 4) * SQ;
  const float* mrow = mkf + b * SQ;
  u16* pw = plds[w];
  f32x4 pf[4];
#pragma unroll
  for (int j = 0; j < 4; ++j)
    pf[j] = __builtin_nontemporal_load(
        reinterpret_cast<const f32x4*>(prow0 + (size_t)j * SQ + lane * 4));
  for (int t = 0; t < 12; ++t) {
    const int bsel = t & 1;
#pragma unroll
    for (int j = 0; j < 4; ++j)
      *reinterpret_cast<f32x4*>(&pbuf[bsel][w * 4 + j][lane * 4]) = pf[j];
    __syncthreads();  // tile t visible to all waves
    if (t < 11) {
#pragma unroll
      for (int j = 0; j < 4; ++j)
        pf[j] = __builtin_nontemporal_load(
            reinterpret_cast<const f32x4*>(prow0 + (size_t)j * SQ + (t + 1) * 256 + lane * 4));
    }
    const int kb = t * 256 + w * 64;  // this wave's 64-key chunk
    // QK^T swapped: s = mfma(K, Q, C=pair+maskbias); D[row=k=lg*4+r][col=q=lr]
    f32x4 s[4];
#pragma unroll
    for (int kt = 0; kt < 4; ++kt) {
      bf16x8 kfv = ld8(kbf + ((size_t)bh * SQ + kb + kt * 16 + lr) * DH + lg * 8);
      f32x4 pv = *reinterpret_cast<const f32x4*>(&pbuf[bsel][lr][w * 64 + kt * 16 + lg * 4]);
      f32x4 mk = *reinterpret_cast<const f32x4*>(mrow + kb + kt * 16 + lg * 4);
      f32x4 c;
      c[0] = fmaf(mqm1, mk[0], pv[0]); c[1] = fmaf(mqm1, mk[1], pv[1]);
      c[2] = fmaf(mqm1, mk[2], pv[2]); c[3] = fmaf(mqm1, mk[3], pv[3]);
      s[kt] = mfma16(kfv, aq, c);
    }
    // max over wave's 64 k: 15 in-reg + 2 shfl (per q=lr)
    f32x4 mx = s[0];
#pragma unroll
    for (int kt = 1; kt < 4; ++kt)
#pragma unroll
      for (int r = 0; r < 4; ++r) mx[r] = fmaxf(mx[r], s[kt][r]);
    float pm = fmaxf(fmaxf(mx[0], mx[1]), fmaxf(mx[2], mx[3]));
    pm = fmaxf(pm, __shfl_xor(pm, 16));
    pm = fmaxf(pm, __shfl_xor(pm, 32));
    if (!__all(pm <= m + 8.f)) {  // defer-max: rare path
      const float mn = fmaxf(m, pm);
      const float alpha = __expf(m - mn);
      m = mn;
      float al[4];
#pragma unroll
      for (int r = 0; r < 4; ++r)
        al[r] = __builtin_bit_cast(
            float, __builtin_amdgcn_ds_bpermute((lg * 4 + r) << 2,
                                                __builtin_bit_cast(int, alpha)));
#pragma unroll
      for (int hf = 0; hf < 2; ++hf)
#pragma unroll
        for (int r = 0; r < 4; ++r) o[hf][r] *= al[r];
      lsum *= alpha;
    }
    float ps = 0.f;
#pragma unroll
    for (int kt = 0; kt < 4; ++kt)
#pragma unroll
      for (int r = 0; r < 4; ++r) {
        float p = __expf(s[kt][r] - m);
        s[kt][r] = p;
        ps += p;
      }
    lsum += ps;  // per-lane partial for q=lr (lg-slice of k)
    // packed P store (row q=lr) + PV
#pragma unroll
    for (int kt = 0; kt < 4; ++kt) {
      u32x2 pk = {pk2(s[kt][0], s[kt][1]), pk2(s[kt][2], s[kt][3])};
      *reinterpret_cast<u32x2*>(pw + lr * 72 + kt * 16 + lg * 4) = pk;
    }
#pragma unroll
    for (int kc = 0; kc < 2; ++kc) {
      bf16x8 pa = ld8(pw + lr * 72 + kc * 32 + lg * 8);
#pragma unroll
      for (int hf = 0; hf < 2; ++hf) {
        bf16x8 bv = ld8(vT + ((size_t)bh * DH + hf * 16 + lr) * SQ + kb + kc * 32 + lg * 8);
        o[hf] = mfma16(pa, bv, o[hf]);  // D[row=q=lg*4+r][col=d=lr]
      }
    }
  }
  lsum += __shfl_xor(lsum, 16);
  lsum += __shfl_xor(lsum, 32);
  // block merge of 4 wave-partials (k-split within block)
#pragma unroll
  for (int r = 0; r < 4; ++r) {
    int row = lg * 4 + r;
    mb[w][row][lr] = o[0][r];
    mb[w][row][16 + lr] = o[1][r];
  }
  if (lane < 16) { mb[w][lane][32] = m; mb[w][lane][33] = lsum; }
  __syncthreads();
#pragma unroll
  for (int it = 0; it < 2; ++it) {
    int q = (tid >> 5) + it * 8;  // 0..15
    int d = tid & 31;
    float m0 = mb[0][q][32], m1 = mb[1][q][32], m2 = mb[2][q][32], m3 = mb[3][q][32];
    float mm = fmaxf(fmaxf(m0, m1), fmaxf(m2, m3));
    float ll = 0.f, oo = 0.f;
#pragma unroll
    for (int w4 = 0; w4 < 4; ++w4) {
      float e = __expf(mb[w4][q][32] - mm);
      ll = fmaf(e, mb[w4][q][33], ll);
      oo = fmaf(e, mb[w4][q][d], oo);
    }
    size_t gi = ((size_t)b * SQ + q0 + q) * 128 + h * 32 + d;
    wa[gi] = f2bf((oo / ll) * gate[gi]);
  }
}

// out = (wa @ Wt2) * zc — 512 threads / 8-wave GEMM split.
__global__ __launch_bounds__(512) void finalk(
    const u16* __restrict__ wa, const u16* __restrict__ WTt2,
    const float* __restrict__ zc, float* __restrict__ out) {
  __shared__ u16 awa[32 * 136];
  const int tid = threadIdx.x, rl = tid >> 4, sub = tid & 15, c0 = sub * 8;
  const size_t grow = (size_t)blockIdx.x * 32 + rl;
  *reinterpret_cast<u32x4*>(&awa[rl * 136 + c0]) =
      *reinterpret_cast<const u32x4*>(wa + grow * 128 + c0);
  __syncthreads();
  const int lane = tid & 63, w = tid >> 6, lr = lane & 15, lg = lane >> 4;
  f32x4 d[2];
  gemm8(awa, WTt2, lr, lg, w, d);
  const int col = w * 16 + lr;
#pragma unroll
  for (int mt = 0; mt < 2; ++mt)
#pragma unroll
    for (int r = 0; r < 4; ++r) {
      size_t gr = (size_t)blockIdx.x * 32 + mt * 16 + lg * 4 + r;
      out[gr * 128 + col] = d[mt][r] * zc[gr * 128 + col];
    }
}

extern "C" void kernel_launch(void* const* d_in, const int* in_sizes, int n_in,
                              void* d_out, int out_size, void* d_ws, size_t ws_size,
                              hipStream_t stream) {
  const float* x_q   = (const float*)d_in[0];
  const float* x_k   = (const float*)d_in[1];
  const int* mask_q  = (const int*)d_in[2];
  const int* mask_k  = (const int*)d_in[3];
  const float* pair  = (const float*)d_in[4];
  const float* scq   = (const float*)d_in[5];
  const float* sck   = (const float*)d_in[6];
  const float* gamma_cq = (const float*)d_in[7];
  const float* Wsq   = (const float*)d_in[8];
  const float* bsq   = (const float*)d_in[9];
  const float* Wbq   = (const float*)d_in[10];
  const float* gamma_ck = (const float*)d_in[11];
  const float* Wsk   = (const float*)d_in[12];
  const float* bsk   = (const float*)d_in[13];
  const float* Wbk   = (const float*)d_in[14];
  const float* Wq    = (const float*)d_in[15];
  const float* bq    = (const float*)d_in[16];
  const float* Wk    = (const float*)d_in[17];
  const float* Wv    = (const float*)d_in[18];
  const float* Wg    = (const float*)d_in[19];
  const float* Wt2   = (const float*)d_in[20];
  const float* Wzc   = (const float*)d_in[21];
  const float* bzc   = (const float*)d_in[22];

  char* wsb = (char*)d_ws;
  u16* WT     = (u16*)(wsb);                 // 10 x 32KB transposed bf16 weights
  u16* qbf    = (u16*)(wsb + 327680);        // [B,H,S,DH] bf16
  u16* kbf    = (u16*)(wsb + 1900544);       // [B,H,S,DH] bf16
  u16* vT     = (u16*)(wsb + 3473408);       // [B,H,DH,S] bf16
  float* gate = (float*)(wsb + 5046272);     // [B,S,C] f32
  float* zc   = (float*)(wsb + 8192000);     // [B,S,C] f32
  u16* wa     = (u16*)(wsb + 11337728);      // [B,S,C] bf16 (ends 12910592)
  float* mkf  = (float*)(wsb + 12910592);    // [B,S] f32 (mask_k - 1)
  float* out  = (float*)d_out;

  PrepSrc ps;
  ps.p[0] = Wsq; ps.p[1] = Wbq; ps.p[2] = Wq; ps.p[3] = Wg; ps.p[4] = Wzc;
  ps.p[5] = Wsk; ps.p[6] = Wbk; ps.p[7] = Wk; ps.p[8] = Wv; ps.p[9] = Wt2;

  hipLaunchKernelGGL(prep, dim3(40), dim3(256), 0, stream, ps, WT);
  hipLaunchKernelGGL(rowblocks, dim3(384), dim3(512), 0, stream,
                     x_q, scq, gamma_cq, bsq, bq, bzc,
                     x_k, sck, gamma_ck, bsk, WT, mask_k,
                     qbf, gate, zc, kbf, vT, mkf);
  hipLaunchKernelGGL(attn, dim3(8 * 192), dim3(256), 0, stream,
                     qbf, kbf, vT, pair, mask_q, mkf, gate, wa);
  hipLaunchKernelGGL(finalk, dim3(192), dim3(512), 0, stream, wa, WT + 9 * 16384, zc, out);
}